// Round 7
// baseline (317.370 us; speedup 1.0000x reference)
//
#include <hip/hip_runtime.h>
#include <stdint.h>

// GMNConv R12 = R11 + (a) scan re-fused into pre_k tail block (R8 form,
// exonerated: the R7-R9 failures were upd_k's LDS overflow, fixed in R10),
// and (b) attn blocks moved from msgattn_k into mid_k (attn depends only on
// pre_k's xb/xt, not on gather; overlaps the PQ GEMM dispatch). msgattn_k
// shrinks to msg_k (msg GEMM only). 5 dispatches total.
//  pre_k    : weight prep + x cast (+U x-cols) + x transpose + histogram + tail scan
//  mid_k    : PQ = xb@WtPQ^T + bPQ (single-shot MFMA) || scatter || attention
//  gather_k : S[n] = sum relu(P[src]+Q[n])  (8/4/1 unroll)
//  msg_k    : msg = S@mW2 + deg*mb2 (MFMA, counted-vmcnt)
//  upd_k    : H1 = relu(U@uW1+b1) [LDS]; H2 = relu(H1@uW2+b2) [LDS];
//             out = x + H2@uW3+b3

typedef unsigned short u16;
typedef __bf16 bf16x8 __attribute__((ext_vector_type(8)));
typedef float f32x4 __attribute__((ext_vector_type(4)));

#define NN 8192
#define DD 128
#define EE 131072
#define GS 128
#define NG 64

__device__ __forceinline__ float bf2f(u16 u){
  return __uint_as_float(((uint32_t)u) << 16);
}
__device__ __forceinline__ u16 f2bf(float f){
  uint32_t x = __float_as_uint(f);
  return (u16)((x + 0x7fffu + ((x >> 16) & 1u)) >> 16);
}
__device__ __forceinline__ void gload16(const u16* g, u16* l){
  __builtin_amdgcn_global_load_lds(
      (const __attribute__((address_space(1))) uint32_t*)(uintptr_t)g,
      (__attribute__((address_space(3))) uint32_t*)(uintptr_t)l, 16, 0, 0);
}
// counted-vmcnt fence + barrier (T4: N>0 keeps newer loads in flight)
template<int N>
__device__ __forceinline__ void wbar(){
  if constexpr (N == 0)      asm volatile("s_waitcnt vmcnt(0)" ::: "memory");
  else if constexpr (N == 1) asm volatile("s_waitcnt vmcnt(1)" ::: "memory");
  else if constexpr (N == 2) asm volatile("s_waitcnt vmcnt(2)" ::: "memory");
  else if constexpr (N == 4) asm volatile("s_waitcnt vmcnt(4)" ::: "memory");
  __builtin_amdgcn_s_barrier();
  __builtin_amdgcn_sched_barrier(0);
}
__device__ __forceinline__ void bar(){
  __builtin_amdgcn_s_barrier();
  __builtin_amdgcn_sched_barrier(0);
}

// ---- gemm_body: C[128x128 tile] = A@Wt^T + bias (msg GEMM) ----
// Wt [Nc][K] row-major bf16; BK=32; counted-vmcnt 2-phase; K multiple of 64.
// LDS: physical 16B-slot p of row r holds logical K-chunk p ^ (r&3).
template<bool DEGBIAS, typename OT>
__device__ __forceinline__ void gemm_body(
    const u16* __restrict__ A, int lda,
    const u16* __restrict__ Wt, const float* __restrict__ bias,
    const int* __restrict__ deg,
    OT* __restrict__ out, int ldc, int K, int bx, int by,
    u16* __restrict__ sh, int t)
{
  u16* As0 = sh;         u16* Bs0 = sh + 4096;
  u16* As1 = sh + 8192;  u16* Bs1 = sh + 12288;
  const int brow = by << 7, bcol = bx << 7;
  const int w = t >> 6, lane = t & 63;
  const int rb = (w >> 1) << 6, cb = (w & 1) << 6;
  const int lr = lane & 15, lq = lane >> 4;

  f32x4 acc[4][4];
  #pragma unroll
  for (int i = 0; i < 4; i++)
    #pragma unroll
    for (int j = 0; j < 4; j++) acc[i][j] = (f32x4){0.f, 0.f, 0.f, 0.f};

  const int s0 = t, s1 = t + 256;
  const int sw0 = (((s0 & 3) ^ ((s0 >> 2) & 3)) << 3);
  const int sw1 = (((s1 & 3) ^ ((s1 >> 2) & 3)) << 3);
  const u16* Ag0 = A  + (size_t)(brow + (s0 >> 2)) * lda + sw0;
  const u16* Ag1 = A  + (size_t)(brow + (s1 >> 2)) * lda + sw1;
  const u16* Bg0 = Wt + (size_t)(bcol + (s0 >> 2)) * K   + sw0;
  const u16* Bg1 = Wt + (size_t)(bcol + (s1 >> 2)) * K   + sw1;
  const int d0 = s0 << 3, d1 = s1 << 3;

  auto stage = [&](int kb, u16* Al, u16* Bl){
    gload16(Ag0 + kb, Al + d0);
    gload16(Ag1 + kb, Al + d1);
    gload16(Bg0 + kb, Bl + d0);
    gload16(Bg1 + kb, Bl + d1);
  };
  const int swr = ((lq ^ (lr & 3)) << 3);
  auto compute = [&](const u16* Asb, const u16* Bsb){
    bf16x8 af[4], bfr[4];
    #pragma unroll
    for (int mi = 0; mi < 4; mi++)
      af[mi] = *(const bf16x8*)&Asb[(rb + mi * 16 + lr) * 32 + swr];
    #pragma unroll
    for (int ni = 0; ni < 4; ni++)
      bfr[ni] = *(const bf16x8*)&Bsb[(cb + ni * 16 + lr) * 32 + swr];
    #pragma unroll
    for (int mi = 0; mi < 4; mi++)
      #pragma unroll
      for (int ni = 0; ni < 4; ni++)
        acc[mi][ni] = __builtin_amdgcn_mfma_f32_16x16x32_bf16(af[mi], bfr[ni], acc[mi][ni], 0, 0, 0);
  };

  stage(0, As0, Bs0);
  const int half = K >> 6;
  for (int i2 = 0; i2 < half; i2++){
    const int kb = i2 << 6;
    stage(kb + 32, As1, Bs1);
    wbar<4>();                      // wait stage(kb); stage(kb+32) stays in flight
    compute(As0, Bs0);
    bar();                          // release As0/Bs0 for overwrite
    if (i2 + 1 < half){
      stage(kb + 64, As0, Bs0);
      wbar<4>();
    } else {
      wbar<0>();
    }
    compute(As1, Bs1);
    bar();
  }

  #pragma unroll
  for (int mi = 0; mi < 4; mi++)
    #pragma unroll
    for (int ni = 0; ni < 4; ni++)
      #pragma unroll
      for (int rr = 0; rr < 4; rr++){
        int grow = brow + rb + mi * 16 + lq * 4 + rr;
        int gcol = bcol + cb + ni * 16 + lr;
        float v = acc[mi][ni][rr];
        if (bias) v += DEGBIAS ? (float)deg[grow] * bias[gcol] : bias[gcol];
        out[(size_t)grow * ldc + gcol] = (OT)f2bf(v);
      }
}

// ---- pq_gemm: C[128x128] = A[128x128] @ Wt[128x128]^T + bias ----
// Single-shot: both 32KB tiles staged once, ONE vmcnt(0) fence, then 64 MFMA
// with no further barriers. Row stride 128 u16 (256B); slot p of row r holds
// logical 16B-chunk p ^ (r&7) (2-way bank alias on read = free).
__device__ __forceinline__ void pq_gemm(
    const u16* __restrict__ A, const u16* __restrict__ Wt,
    const float* __restrict__ bias, u16* __restrict__ out,
    int bx, int by, u16* __restrict__ sh, int t)
{
  u16* As = sh;             // 16384 u16
  u16* Bs = sh + 16384;     // 16384 u16
  const int brow = by << 7, bcol = bx << 7;
  const int w = t >> 6, lane = t & 63;
  const int rb = (w >> 1) << 6, cb = (w & 1) << 6;
  const int lr = lane & 15, lq = lane >> 4;

  #pragma unroll
  for (int i = 0; i < 8; i++){
    int sg = i * 256 + t;
    int r = sg >> 4, p = sg & 15;
    int l = p ^ (r & 7);
    gload16(A  + (size_t)(brow + r) * 128 + (l << 3), As + sg * 8);
    gload16(Wt + (size_t)(bcol + r) * 128 + (l << 3), Bs + sg * 8);
  }
  wbar<0>();

  f32x4 acc[4][4];
  #pragma unroll
  for (int i = 0; i < 4; i++)
    #pragma unroll
    for (int j = 0; j < 4; j++) acc[i][j] = (f32x4){0.f, 0.f, 0.f, 0.f};

  #pragma unroll
  for (int kb = 0; kb < 4; kb++){
    bf16x8 af[4], bfr[4];
    #pragma unroll
    for (int mi = 0; mi < 4; mi++){
      int row = rb + mi * 16 + lr;
      af[mi] = *(const bf16x8*)&As[(row << 7) + ((((kb << 2) | lq) ^ (row & 7)) << 3)];
    }
    #pragma unroll
    for (int ni = 0; ni < 4; ni++){
      int row = cb + ni * 16 + lr;
      bfr[ni] = *(const bf16x8*)&Bs[(row << 7) + ((((kb << 2) | lq) ^ (row & 7)) << 3)];
    }
    #pragma unroll
    for (int mi = 0; mi < 4; mi++)
      #pragma unroll
      for (int ni = 0; ni < 4; ni++)
        acc[mi][ni] = __builtin_amdgcn_mfma_f32_16x16x32_bf16(af[mi], bfr[ni], acc[mi][ni], 0, 0, 0);
  }

  #pragma unroll
  for (int mi = 0; mi < 4; mi++)
    #pragma unroll
    for (int ni = 0; ni < 4; ni++)
      #pragma unroll
      for (int rr = 0; rr < 4; rr++){
        int grow = brow + rb + mi * 16 + lq * 4 + rr;
        int gcol = bcol + cb + ni * 16 + lr;
        out[(size_t)grow * 1024 + gcol] = f2bf(acc[mi][ni][rr] + bias[gcol]);
      }
}

// ---- pre_k: weights | cast x | transpose x | histogram + tail scan ----
__global__ __launch_bounds__(256)
void pre_k(const float* __restrict__ mW1, const float* __restrict__ mb1,
           const float* __restrict__ mW2, const float* __restrict__ uW1,
           const float* __restrict__ uW2, const float* __restrict__ uW3,
           const float* __restrict__ x1, const float* __restrict__ x2,
           const int* __restrict__ ei1, const int* __restrict__ ei2,
           u16* __restrict__ WtPQ, float* __restrict__ bPQ,
           u16* __restrict__ Wtm2, u16* __restrict__ Wtu1,
           u16* __restrict__ Wtu2, u16* __restrict__ Wtu3,
           u16* __restrict__ xb, u16* __restrict__ xt,
           u16* __restrict__ U, int* __restrict__ deg,
           int* __restrict__ done,
           int* __restrict__ offs1, int* __restrict__ cur1,
           int* __restrict__ offs2, int* __restrict__ cur2)
{
  __shared__ u16 T[8704];     // 64*136, transpose branch only
  __shared__ int part[256];   // tail-scan branch only
  __shared__ int lastf;
  int b = blockIdx.x, t = threadIdx.x;
  if (b < 2692){
    // weight prep
    if (b < 512){                       // WtPQ [1024][128]
      int idx = b * 256 + t; int c = idx >> 7, k = idx & 127;
      int row = (c < 512) ? k : 128 + k;
      WtPQ[idx] = f2bf(mW1[(size_t)row * 512 + (c & 511)]);
    } else if (b < 1024){               // Wtm2 [256][512]
      int idx = (b - 512) * 256 + t; int c = idx >> 9, k = idx & 511;
      Wtm2[idx] = f2bf(mW2[(size_t)k * 256 + c]);
    } else if (b < 2048){               // Wtu1 [512][512]
      int idx = (b - 1024) * 256 + t; int c = idx >> 9, k = idx & 511;
      Wtu1[idx] = f2bf(uW1[(size_t)k * 512 + c]);
    } else if (b < 2560){               // Wtu2 [256][512]
      int idx = (b - 2048) * 256 + t; int c = idx >> 9, k = idx & 511;
      Wtu2[idx] = f2bf(uW2[(size_t)k * 256 + c]);
    } else if (b < 2688){               // Wtu3 [128][256]
      int idx = (b - 2560) * 256 + t; int c = idx >> 8, k = idx & 255;
      Wtu3[idx] = f2bf(uW3[(size_t)k * 128 + c]);
    } else {                            // bPQ [1024]
      int idx = (b - 2688) * 256 + t;
      bPQ[idx] = (idx < 512) ? 0.f : mb1[idx - 512];
    }
  } else if (b < 4740){
    // cast x -> xb + U x-columns (float4 vectorized)
    int a = b - 2692;
    int side = a >> 10, blk = a & 1023;
    const float* x = side ? x2 : x1;
    int i4 = blk * 256 + t;                 // float4 index within side
    float4 v = *(const float4*)&x[(size_t)i4 * 4];
    uint2 pk;
    pk.x = (uint32_t)f2bf(v.x) | ((uint32_t)f2bf(v.y) << 16);
    pk.y = (uint32_t)f2bf(v.z) | ((uint32_t)f2bf(v.w) << 16);
    *(uint2*)&xb[(size_t)side * NN * DD + (size_t)i4 * 4] = pk;
    int n = i4 >> 5, d = (i4 << 2) & 127;
    *(uint2*)&U[((size_t)side * NN + n) * 512 + 384 + d] = pk;
  } else if (b < 4996){
    // transpose: xt[side][d][n] = bf16(x[side][n][d]), 64-node tile
    int a = b - 4740;
    int side = a >> 7, blk = a & 127;
    const float* x = side ? x2 : x1;
    u16* dst = xt + (size_t)side * DD * NN;
    const int n0 = blk * 64;
    #pragma unroll
    for (int i = 0; i < 8; i++){
      int s = i * 256 + t;
      int r = s >> 5, c4 = (s & 31) << 2;
      float4 v = *(const float4*)&x[(size_t)(n0 + r) * DD + c4];
      uint2 pk;
      pk.x = (uint32_t)f2bf(v.x) | ((uint32_t)f2bf(v.y) << 16);
      pk.y = (uint32_t)f2bf(v.z) | ((uint32_t)f2bf(v.w) << 16);
      *(uint2*)&T[r * 136 + c4] = pk;
    }
    __syncthreads();
    #pragma unroll
    for (int i = 0; i < 8; i++){
      int s = i * 256 + t;
      int d = s >> 4, n4 = (s & 15) << 2;
      uint32_t a0 = T[(n4 + 0) * 136 + d];
      uint32_t a1 = T[(n4 + 1) * 136 + d];
      uint32_t a2 = T[(n4 + 2) * 136 + d];
      uint32_t a3 = T[(n4 + 3) * 136 + d];
      uint2 pk; pk.x = a0 | (a1 << 16); pk.y = a2 | (a3 << 16);
      *(uint2*)(dst + (size_t)d * NN + n0 + n4) = pk;
    }
  } else {
    // histogram + tail-block scan
    int a = b - 4996;
    int side = a >> 9, blk = a & 511;
    const int* ei = side ? ei2 : ei1;
    int e = blk * 256 + t;
    atomicAdd(&deg[side * NN + ei[e]], 1);
    __threadfence();
    __syncthreads();   // drain ALL block threads' atomics before election
    if (t == 0) lastf = (atomicAdd(done, 1) == 1023);
    __syncthreads();
    if (lastf){
      __threadfence();
      for (int sd = 0; sd < 2; sd++){
        const int* d = deg + sd * NN;
        int* offs = sd ? offs2 : offs1;
        int* cur  = sd ? cur2  : cur1;
        const int base = t * 32;
        int loc[32];
        int s = 0;
        #pragma unroll
        for (int i = 0; i < 32; i++){
          loc[i] = s;
          s += __hip_atomic_load(&d[base + i], __ATOMIC_RELAXED, __HIP_MEMORY_SCOPE_AGENT);
        }
        part[t] = s;
        __syncthreads();
        for (int off = 1; off < 256; off <<= 1){
          int v = (t >= off) ? part[t - off] : 0;
          __syncthreads();
          part[t] += v;
          __syncthreads();
        }
        int pre = (t == 0) ? 0 : part[t - 1];
        #pragma unroll
        for (int i = 0; i < 32; i++){
          int o = pre + loc[i];
          offs[base + i] = o;
          cur[base + i]  = o;
        }
        if (t == 255) offs[NN] = part[255];
        __syncthreads();
      }
    }
  }
}

// ---- mid_k: PQ GEMM (single-shot) | scatter edges | cross-attention ----
__global__ __launch_bounds__(256)
void mid_k(const u16* __restrict__ xb, const u16* __restrict__ WtPQ,
           const float* __restrict__ bPQ, u16* __restrict__ PQ,
           const int* __restrict__ ei1, const int* __restrict__ ei2,
           int* __restrict__ cur1, int* __restrict__ cur2,
           int* __restrict__ srt1, int* __restrict__ srt2,
           const u16* __restrict__ xt, u16* __restrict__ U)
{
  __shared__ u16 sh[32768];   // pq: 64KB; attn: XaS 8704 + XbS 17408 = 52KB
  const int b = blockIdx.x, t = threadIdx.x;
  if (b < 1024){
    pq_gemm(xb, WtPQ, bPQ, PQ, b >> 7, b & 127, sh, t);
    return;
  }
  if (b < 2048){
    int a = b - 1024;
    int side = a >> 9, blk = a & 511;
    const int* ei = side ? ei2 : ei1;
    int* cur = side ? cur2 : cur1;
    int* srt = side ? srt2 : srt1;
    int e = blk * 256 + t;
    int tgt = ei[e], src = ei[EE + e];
    int p = atomicAdd(&cur[tgt], 1);
    srt[p] = src;
    return;
  }
  // ---- block-diagonal cross-attention (depends only on pre_k) ----
  const int a = b - 2048;
  const int side = a >> 7;
  const int g = a & 63, h = (a >> 6) & 1;
  const u16* Xa = xb + (size_t)side * NN * DD;
  const u16* Xb = xb + (size_t)(1 - side) * NN * DD;
  const u16* Xt = xt + (size_t)(1 - side) * DD * NN;
  u16* Uside = U + (size_t)side * NN * 512;

  u16* XaS = sh;            // 64*136
  u16* XbS = sh + 8704;     // 128*136

  const int w = t >> 6, lane = t & 63;
  const int lr = lane & 15, lq = lane >> 4;

  {
    const u16* sa = Xa + ((size_t)g * GS + h * 64) * DD;
    #pragma unroll
    for (int i = 0; i < 4; i++){
      int s = i * 256 + t; int r = s >> 4, c8 = (s & 15) << 3;
      *(uint4*)&XaS[r * 136 + c8] = *(const uint4*)(sa + (size_t)r * DD + c8);
    }
    const u16* sb = Xb + (size_t)g * GS * DD;
    #pragma unroll
    for (int i = 0; i < 8; i++){
      int s = i * 256 + t; int r = s >> 4, c8 = (s & 15) << 3;
      *(uint4*)&XbS[r * 136 + c8] = *(const uint4*)(sb + (size_t)r * DD + c8);
    }
  }
  __syncthreads();

  f32x4 sc[8];
  #pragma unroll
  for (int ct = 0; ct < 8; ct++) sc[ct] = (f32x4){0.f, 0.f, 0.f, 0.f};
  #pragma unroll
  for (int kb = 0; kb < 4; kb++){
    bf16x8 aa = *(const bf16x8*)&XaS[(w * 16 + lr) * 136 + kb * 32 + (lq << 3)];
    #pragma unroll
    for (int ct = 0; ct < 8; ct++){
      bf16x8 bb = *(const bf16x8*)&XbS[(ct * 16 + lr) * 136 + kb * 32 + (lq << 3)];
      sc[ct] = __builtin_amdgcn_mfma_f32_16x16x32_bf16(aa, bb, sc[ct], 0, 0, 0);
    }
  }
  float inv[4];
  #pragma unroll
  for (int rr = 0; rr < 4; rr++){
    float m = sc[0][rr];
    #pragma unroll
    for (int ct = 1; ct < 8; ct++) m = fmaxf(m, sc[ct][rr]);
    #pragma unroll
    for (int sh_ = 1; sh_ < 16; sh_ <<= 1) m = fmaxf(m, __shfl_xor(m, sh_, 64));
    float s = 0.f;
    #pragma unroll
    for (int ct = 0; ct < 8; ct++){
      float e = __expf(sc[ct][rr] - m);
      sc[ct][rr] = e; s += e;
    }
    #pragma unroll
    for (int sh_ = 1; sh_ < 16; sh_ <<= 1) s += __shfl_xor(s, sh_, 64);
    inv[rr] = 1.f / s;
  }
  #pragma unroll
  for (int ct = 0; ct < 8; ct++)
    #pragma unroll
    for (int rr = 0; rr < 4; rr++)
      XaS[(w * 16 + lq * 4 + rr) * 136 + ct * 16 + lr] = f2bf(sc[ct][rr] * inv[rr]);
  __syncthreads();

  f32x4 o[8];
  #pragma unroll
  for (int ct = 0; ct < 8; ct++) o[ct] = (f32x4){0.f, 0.f, 0.f, 0.f};
  #pragma unroll
  for (int kb = 0; kb < 4; kb++){
    bf16x8 aa = *(const bf16x8*)&XaS[(w * 16 + lr) * 136 + kb * 32 + (lq << 3)];
    #pragma unroll
    for (int ct = 0; ct < 8; ct++){
      bf16x8 bb = *(const bf16x8*)(Xt + (size_t)(ct * 16 + lr) * NN + g * GS + kb * 32 + (lq << 3));
      o[ct] = __builtin_amdgcn_mfma_f32_16x16x32_bf16(aa, bb, o[ct], 0, 0, 0);
    }
  }
  const u16* XaG = Xa + ((size_t)g * GS + h * 64) * DD;
  #pragma unroll
  for (int ct = 0; ct < 8; ct++)
    #pragma unroll
    for (int rr = 0; rr < 4; rr++){
      int row = w * 16 + lq * 4 + rr, col = ct * 16 + lr;
      float xa = bf2f(XaG[(size_t)row * DD + col]);
      Uside[((size_t)g * GS + h * 64 + row) * 512 + 256 + col] = f2bf(xa - o[ct][rr]);
    }
}

// ---- gather: S[n] = sum relu(P[src]+Q[n]); 1 wave = 1 node; 8/4/1 tiers ----
__global__ __launch_bounds__(256)
void gather_k(const int* __restrict__ offs1, const int* __restrict__ srt1,
              const int* __restrict__ offs2, const int* __restrict__ srt2,
              const u16* __restrict__ PQ, u16* __restrict__ S)
{
  const int side = blockIdx.y;
  const int* offs = side ? offs2 : offs1;
  const int* srt  = side ? srt2  : srt1;
  const u16* base = PQ + (size_t)side * NN * 1024;
  u16* Sb = S + (size_t)side * NN * 512;

  const int node = (blockIdx.x << 2) + (threadIdx.x >> 6);
  const int lane = threadIdx.x & 63;
  const int beg = offs[node], end = offs[node + 1];

  uint4 qv = *(const uint4*)(base + (size_t)node * 1024 + 512 + (lane << 3));
  float q[8];
  {
    uint32_t qw[4] = {qv.x, qv.y, qv.z, qv.w};
    #pragma unroll
    for (int i = 0; i < 4; i++){
      q[i * 2]     = bf2f((u16)(qw[i] & 0xffffu));
      q[i * 2 + 1] = bf2f((u16)(qw[i] >> 16));
    }
  }
  float acc[8] = {0.f,0.f,0.f,0.f,0.f,0.f,0.f,0.f};

  int e = beg;
  for (; e + 7 < end; e += 8){
    int sx[8];
    #pragma unroll
    for (int i = 0; i < 8; i++) sx[i] = srt[e + i];
    uint4 pv[8];
    #pragma unroll
    for (int i = 0; i < 8; i++)
      pv[i] = *(const uint4*)(base + (size_t)sx[i] * 1024 + (lane << 3));
    #pragma unroll
    for (int i = 0; i < 8; i++){
      uint32_t w0[4] = {pv[i].x, pv[i].y, pv[i].z, pv[i].w};
      #pragma unroll
      for (int j = 0; j < 4; j++){
        acc[j*2]   += fmaxf(bf2f((u16)(w0[j] & 0xffffu)) + q[j*2],   0.f);
        acc[j*2+1] += fmaxf(bf2f((u16)(w0[j] >> 16))     + q[j*2+1], 0.f);
      }
    }
  }
  for (; e + 3 < end; e += 4){
    int sx[4];
    #pragma unroll
    for (int i = 0; i < 4; i++) sx[i] = srt[e + i];
    uint4 pv[4];
    #pragma unroll
    for (int i = 0; i < 4; i++)
      pv[i] = *(const uint4*)(base + (size_t)sx[i] * 1024 + (lane << 3));
    #pragma unroll
    for (int i = 0; i < 4; i++){
      uint32_t w0[4] = {pv[i].x, pv[i].y, pv[i].z, pv[i].w};
      #pragma unroll
      for (int j = 0; j < 4; j++){
        acc[j*2]   += fmaxf(bf2f((u16)(w0[j] & 0xffffu)) + q[j*2],   0.f);
        acc[j*2+1] += fmaxf(bf2f((u16)(w0[j] >> 16))     + q[j*2+1], 0.f);
      }
    }
  }
  for (; e < end; e++){
    int sA = srt[e];
    uint4 pA = *(const uint4*)(base + (size_t)sA * 1024 + (lane << 3));
    uint32_t aw[4] = {pA.x, pA.y, pA.z, pA.w};
    #pragma unroll
    for (int i = 0; i < 4; i++){
      acc[i*2]   += fmaxf(bf2f((u16)(aw[i] & 0xffffu)) + q[i*2],   0.f);
      acc[i*2+1] += fmaxf(bf2f((u16)(aw[i] >> 16))     + q[i*2+1], 0.f);
    }
  }
  uint4 pk;
  pk.x = (uint32_t)f2bf(acc[0]) | ((uint32_t)f2bf(acc[1]) << 16);
  pk.y = (uint32_t)f2bf(acc[2]) | ((uint32_t)f2bf(acc[3]) << 16);
  pk.z = (uint32_t)f2bf(acc[4]) | ((uint32_t)f2bf(acc[5]) << 16);
  pk.w = (uint32_t)f2bf(acc[6]) | ((uint32_t)f2bf(acc[7]) << 16);
  *(uint4*)(Sb + (size_t)node * 512 + (lane << 3)) = pk;
}

// ---- msg_k: msg = S @ Wtm2^T + deg*mb2 -> U cols 0..255 ----
__global__ __launch_bounds__(256)
void msg_k(const u16* __restrict__ S, const u16* __restrict__ Wtm2,
           const float* __restrict__ mb2, const int* __restrict__ deg,
           u16* __restrict__ U)
{
  __shared__ u16 sh[16384];
  gemm_body<true,u16>(S, 512, Wtm2, mb2, deg,
                      U, 512, 512, blockIdx.x >> 7, blockIdx.x & 127,
                      sh, threadIdx.x);
}

// ---- upd_k: fused update net. 64 rows/block, 512 threads (2x4 wave grid).
// H1 [64][520], H2 [64][264] in LDS; B weights streamed counted-vmcnt;
// G1's A operand loads straight to registers from global (L2-hot, 4x reuse).
__global__ __launch_bounds__(512)
void upd_k(const u16* __restrict__ U,
           const u16* __restrict__ Wtu1, const float* __restrict__ ub1,
           const u16* __restrict__ Wtu2, const float* __restrict__ ub2,
           const u16* __restrict__ Wtu3, const float* __restrict__ ub3,
           const float* __restrict__ x1, const float* __restrict__ x2,
           float* __restrict__ out)
{
  __shared__ u16 sh[66560];   // 133120 B
  u16* H1s  = sh;             // 64*520 = 33280
  u16* H2s  = sh + 33280;     // 64*264 = 16896
  u16* Bst0 = sh + 50176;     // 8192 (1024 slots of 8)
  u16* Bst1 = sh + 58368;     // 8192

  const int t = threadIdx.x;
  const int w = t >> 6, lane = t & 63;
  const int wr = w >> 2, wc = w & 3;     // 2 (rows) x 4 (cols) waves
  const int lr = lane & 15, lq = lane >> 4;
  const int r0 = blockIdx.x << 6;

  const int sB0 = t, sB1 = t + 512;      // B slots
  const int cB0 = sB0 >> 2, cB1 = sB1 >> 2;
  const int swB0 = (((sB0 & 3) ^ (cB0 & 3)) << 3);
  const int swB1 = (((sB1 & 3) ^ (cB1 & 3)) << 3);
  const int swr = ((lq ^ (lr & 3)) << 3);

  f32x4 acc[2][4];
  auto zacc = [&](){
    #pragma unroll
    for (int i = 0; i < 2; i++)
      #pragma unroll
      for (int j = 0; j < 4; j++) acc[i][j] = (f32x4){0.f, 0.f, 0.f, 0.f};
  };

  // ---- G1: H1 = relu(U @ Wtu1^T + b1), K=512, 512 cols in 2 halves ----
  bf16x8 afA[2], afB[2];
  auto ldA = [&](int kb, bf16x8 (&af)[2]){
    #pragma unroll
    for (int mi = 0; mi < 2; mi++)
      af[mi] = *(const bf16x8*)&U[(size_t)(r0 + wr * 32 + mi * 16 + lr) * 512 + kb + (lq << 3)];
  };
  auto compA = [&](const bf16x8 (&af)[2], const u16* Bsb){
    bf16x8 bfv[4];
    #pragma unroll
    for (int ct = 0; ct < 4; ct++)
      bfv[ct] = *(const bf16x8*)&Bsb[(wc * 64 + ct * 16 + lr) * 32 + swr];
    #pragma unroll
    for (int mi = 0; mi < 2; mi++)
      #pragma unroll
      for (int ct = 0; ct < 4; ct++)
        acc[mi][ct] = __builtin_amdgcn_mfma_f32_16x16x32_bf16(af[mi], bfv[ct], acc[mi][ct], 0, 0, 0);
  };
  for (int hN = 0; hN < 2; hN++){
    zacc();
    auto stB = [&](int kb, u16* dst){
      gload16(Wtu1 + (size_t)(hN * 256 + cB0) * 512 + kb + swB0, dst + sB0 * 8);
      gload16(Wtu1 + (size_t)(hN * 256 + cB1) * 512 + kb + swB1, dst + sB1 * 8);
    };
    stB(0, Bst0);
    ldA(0, afA);
    for (int i2 = 0; i2 < 8; i2++){
      const int kb = i2 << 6;
      stB(kb + 32, Bst1); ldA(kb + 32, afB);
      wbar<4>();                     // waits stB(kb)+ldA(kb); newer 4 in flight
      compA(afA, Bst0);
      bar();
      if (i2 < 7){
        stB(kb + 64, Bst0); ldA(kb + 64, afA);
        wbar<4>();
      } else {
        wbar<0>();
      }
      compA(afB, Bst1);
      bar();
    }
    #pragma unroll
    for (int mi = 0; mi < 2; mi++)
      #pragma unroll
      for (int ct = 0; ct < 4; ct++)
        #pragma unroll
        for (int rr = 0; rr < 4; rr++){
          int row = wr * 32 + mi * 16 + lq * 4 + rr;
          int col = wc * 64 + ct * 16 + lr;
          float v = acc[mi][ct][rr] + ub1[hN * 256 + col];
          H1s[row * 520 + hN * 256 + col] = f2bf(fmaxf(v, 0.f));
        }
  }
  __syncthreads();

  // ---- G2: H2 = relu(H1 @ Wtu2^T + b2), K=512, 256 cols ----
  zacc();
  {
    auto stB = [&](int kb, u16* dst){
      gload16(Wtu2 + (size_t)cB0 * 512 + kb + swB0, dst + sB0 * 8);
      gload16(Wtu2 + (size_t)cB1 * 512 + kb + swB1, dst + sB1 * 8);
    };
    auto comp = [&](int kb, const u16* Bsb){
      bf16x8 af[2], bfv[4];
      #pragma unroll
      for (int mi = 0; mi < 2; mi++)
        af[mi] = *(const bf16x8*)&H1s[(wr * 32 + mi * 16 + lr) * 520 + kb + (lq << 3)];
      #pragma unroll
      for (int ct = 0; ct < 4; ct++)
        bfv[ct] = *(const bf16x8*)&Bsb[(wc * 64 + ct * 16 + lr) * 32 + swr];
      #pragma unroll
      for (int mi = 0; mi < 2; mi++)
        #pragma unroll
        for (int ct = 0; ct < 4; ct++)
          acc[mi][ct] = __builtin_amdgcn_mfma_f32_16x16x32_bf16(af[mi], bfv[ct], acc[mi][ct], 0, 0, 0);
    };
    stB(0, Bst0);
    for (int i2 = 0; i2 < 8; i2++){
      const int kb = i2 << 6;
      stB(kb + 32, Bst1);
      wbar<2>();
      comp(kb, Bst0);
      bar();
      if (i2 < 7){
        stB(kb + 64, Bst0);
        wbar<2>();
      } else {
        wbar<0>();
      }
      comp(kb + 32, Bst1);
      bar();
    }
    #pragma unroll
    for (int mi = 0; mi < 2; mi++)
      #pragma unroll
      for (int ct = 0; ct < 4; ct++)
        #pragma unroll
        for (int rr = 0; rr < 4; rr++){
          int row = wr * 32 + mi * 16 + lq * 4 + rr;
          int col = wc * 64 + ct * 16 + lr;
          H2s[row * 264 + col] = f2bf(fmaxf(acc[mi][ct][rr] + ub2[col], 0.f));
        }
  }
  __syncthreads();

  // ---- G3: out = x + H2 @ Wtu3^T + b3, K=256, 128 cols ----
  zacc();
  {
    auto stB = [&](int kb, u16* dst){
      gload16(Wtu3 + (size_t)cB0 * 256 + kb + swB0, dst + sB0 * 8);   // 512 slots
    };
    auto comp = [&](int kb, const u16* Bsb){
      bf16x8 af[2], bfv[2];
      #pragma unroll
      for (int mi = 0; mi < 2; mi++)
        af[mi] = *(const bf16x8*)&H2s[(wr * 32 + mi * 16 + lr) * 264 + kb + (lq << 3)];
      #pragma unroll
      for (int ct = 0; ct < 2; ct++)
        bfv[ct] = *(const bf16x8*)&Bsb[(wc * 32 + ct * 16 + lr) * 32 + swr];
      #pragma unroll
      for (int mi = 0; mi < 2; mi++)
        #pragma unroll
        for (int ct = 0; ct < 2; ct++)
          acc[mi][ct] = __builtin_amdgcn_mfma_f32_16x16x32_bf16(af[mi], bfv[ct], acc[mi][ct], 0, 0, 0);
    };
    stB(0, Bst0);
    for (int i2 = 0; i2 < 4; i2++){
      const int kb = i2 << 6;
      stB(kb + 32, Bst1);
      wbar<1>();
      comp(kb, Bst0);
      bar();
      if (i2 < 3){
        stB(kb + 64, Bst0);
        wbar<1>();
      } else {
        wbar<0>();
      }
      comp(kb + 32, Bst1);
      bar();
    }
    #pragma unroll
    for (int mi = 0; mi < 2; mi++)
      #pragma unroll
      for (int ct = 0; ct < 2; ct++)
        #pragma unroll
        for (int rr = 0; rr < 4; rr++){
          int row = wr * 32 + mi * 16 + lq * 4 + rr;
          int col = wc * 32 + ct * 16 + lr;
          int grow = r0 + row;
          const float* rp = (grow < NN) ? x1 : x2;
          float v = acc[mi][ct][rr] + ub3[col]
                  + rp[(size_t)(grow & (NN - 1)) * 128 + col];
          out[(size_t)grow * 128 + col] = v;
        }
  }
}

extern "C" void kernel_launch(void* const* d_in, const int* in_sizes, int n_in,
                              void* d_out, int out_size, void* d_ws, size_t ws_size,
                              hipStream_t stream)
{
  const float* x1  = (const float*)d_in[0];
  const int*   ei1 = (const int*)  d_in[1];
  const float* x2  = (const float*)d_in[3];
  const int*   ei2 = (const int*)  d_in[4];
  const float* mW1 = (const float*)d_in[6];
  const float* mb1 = (const float*)d_in[7];
  const float* mW2 = (const float*)d_in[8];
  const float* mb2 = (const float*)d_in[9];
  const float* uW1 = (const float*)d_in[10];
  const float* ub1 = (const float*)d_in[11];
  const float* uW2 = (const float*)d_in[12];
  const float* ub2 = (const float*)d_in[13];
  const float* uW3 = (const float*)d_in[14];
  const float* ub3 = (const float*)d_in[15];
  float* out = (float*)d_out;

  char* w = (char*)d_ws;
  auto alloc = [&](size_t b){ char* p = w; w += (b + 255) & ~(size_t)255; return p; };
  u16*  S    = (u16*)alloc((size_t)2 * NN * 512 * 2);
  u16*  PQ   = (u16*)alloc((size_t)2 * NN * 1024 * 2);
  u16*  xb   = (u16*)alloc((size_t)2 * NN * DD * 2);
  u16*  xt   = (u16*)alloc((size_t)2 * DD * NN * 2);
  u16*  U    = (u16*)alloc((size_t)2 * NN * 512 * 2);
  int*  deg  = (int*)alloc((size_t)2 * NN * 4);
  int*  done = (int*)alloc(256);
  int*  offs1 = (int*)alloc((NN + 1) * 4);
  int*  offs2 = (int*)alloc((NN + 1) * 4);
  int*  cur1  = (int*)alloc(NN * 4);
  int*  cur2  = (int*)alloc(NN * 4);
  int*  srt1  = (int*)alloc((size_t)EE * 4);
  int*  srt2  = (int*)alloc((size_t)EE * 4);
  u16*  WtPQ = (u16*)alloc(1024 * 128 * 2);
  float* bPQ = (float*)alloc(1024 * 4);
  u16*  Wtm2 = (u16*)alloc(256 * 512 * 2);
  u16*  Wtu1 = (u16*)alloc(512 * 512 * 2);
  u16*  Wtu2 = (u16*)alloc(256 * 512 * 2);
  u16*  Wtu3 = (u16*)alloc(128 * 256 * 2);

  hipMemsetAsync(deg, 0, (size_t)2 * NN * 4 + 256, stream);

  pre_k<<<4996 + 1024, 256, 0, stream>>>(
      mW1, mb1, mW2, uW1, uW2, uW3, x1, x2, ei1, ei2,
      WtPQ, bPQ, Wtm2, Wtu1, Wtu2, Wtu3, xb, xt, U, deg, done,
      offs1, cur1, offs2, cur2);

  mid_k<<<2304, 256, 0, stream>>>(xb, WtPQ, bPQ, PQ, ei1, ei2,
                                  cur1, cur2, srt1, srt2, xt, U);

  gather_k<<<dim3(NN / 4, 2), 256, 0, stream>>>(offs1, srt1, offs2, srt2, PQ, S);

  msg_k<<<256, 256, 0, stream>>>(S, Wtm2, mb2, deg, U);

  upd_k<<<256, 512, 0, stream>>>(U, Wtu1, ub1, Wtu2, ub2, Wtu3, ub3,
                                 x1, x2, out);
}

// Round 8
// 229.000 us; speedup vs baseline: 1.3859x; 1.3859x over previous
//
#include <hip/hip_runtime.h>
#include <stdint.h>

// GMNConv R13 = R12 with the fused scan REVERTED to the separate scan_k
// dispatch. R12's profile showed the fusion cost ~95us: per-thread
// __threadfence() across 1024 histogram blocks serializes L2 writebacks on
// 8 non-coherent XCDs (pre_k 120us @ 0.7% VALUBusy). The 2-block scan_k
// bubble (~7us) is the right design. The attn-into-mid_k move is KEPT
// (R12 passed; sync-neutral).
//  pre_k    : weight prep + x cast (+U x-cols) + x transpose + histogram
//  scan_k   : exclusive prefix scan of deg -> offs/cur
//  mid_k    : PQ = xb@WtPQ^T + bPQ (single-shot MFMA) || scatter || attention
//  gather_k : S[n] = sum relu(P[src]+Q[n])  (8/4/1 unroll)
//  msg_k    : msg = S@mW2 + deg*mb2 (MFMA, counted-vmcnt)
//  upd_k    : H1 = relu(U@uW1+b1) [LDS]; H2 = relu(H1@uW2+b2) [LDS];
//             out = x + H2@uW3+b3

typedef unsigned short u16;
typedef __bf16 bf16x8 __attribute__((ext_vector_type(8)));
typedef float f32x4 __attribute__((ext_vector_type(4)));

#define NN 8192
#define DD 128
#define EE 131072
#define GS 128
#define NG 64

__device__ __forceinline__ float bf2f(u16 u){
  return __uint_as_float(((uint32_t)u) << 16);
}
__device__ __forceinline__ u16 f2bf(float f){
  uint32_t x = __float_as_uint(f);
  return (u16)((x + 0x7fffu + ((x >> 16) & 1u)) >> 16);
}
__device__ __forceinline__ void gload16(const u16* g, u16* l){
  __builtin_amdgcn_global_load_lds(
      (const __attribute__((address_space(1))) uint32_t*)(uintptr_t)g,
      (__attribute__((address_space(3))) uint32_t*)(uintptr_t)l, 16, 0, 0);
}
// counted-vmcnt fence + barrier (T4: N>0 keeps newer loads in flight)
template<int N>
__device__ __forceinline__ void wbar(){
  if constexpr (N == 0)      asm volatile("s_waitcnt vmcnt(0)" ::: "memory");
  else if constexpr (N == 1) asm volatile("s_waitcnt vmcnt(1)" ::: "memory");
  else if constexpr (N == 2) asm volatile("s_waitcnt vmcnt(2)" ::: "memory");
  else if constexpr (N == 4) asm volatile("s_waitcnt vmcnt(4)" ::: "memory");
  __builtin_amdgcn_s_barrier();
  __builtin_amdgcn_sched_barrier(0);
}
__device__ __forceinline__ void bar(){
  __builtin_amdgcn_s_barrier();
  __builtin_amdgcn_sched_barrier(0);
}

// ---- gemm_body: C[128x128 tile] = A@Wt^T + bias (msg GEMM) ----
// Wt [Nc][K] row-major bf16; BK=32; counted-vmcnt 2-phase; K multiple of 64.
// LDS: physical 16B-slot p of row r holds logical K-chunk p ^ (r&3).
template<bool DEGBIAS, typename OT>
__device__ __forceinline__ void gemm_body(
    const u16* __restrict__ A, int lda,
    const u16* __restrict__ Wt, const float* __restrict__ bias,
    const int* __restrict__ deg,
    OT* __restrict__ out, int ldc, int K, int bx, int by,
    u16* __restrict__ sh, int t)
{
  u16* As0 = sh;         u16* Bs0 = sh + 4096;
  u16* As1 = sh + 8192;  u16* Bs1 = sh + 12288;
  const int brow = by << 7, bcol = bx << 7;
  const int w = t >> 6, lane = t & 63;
  const int rb = (w >> 1) << 6, cb = (w & 1) << 6;
  const int lr = lane & 15, lq = lane >> 4;

  f32x4 acc[4][4];
  #pragma unroll
  for (int i = 0; i < 4; i++)
    #pragma unroll
    for (int j = 0; j < 4; j++) acc[i][j] = (f32x4){0.f, 0.f, 0.f, 0.f};

  const int s0 = t, s1 = t + 256;
  const int sw0 = (((s0 & 3) ^ ((s0 >> 2) & 3)) << 3);
  const int sw1 = (((s1 & 3) ^ ((s1 >> 2) & 3)) << 3);
  const u16* Ag0 = A  + (size_t)(brow + (s0 >> 2)) * lda + sw0;
  const u16* Ag1 = A  + (size_t)(brow + (s1 >> 2)) * lda + sw1;
  const u16* Bg0 = Wt + (size_t)(bcol + (s0 >> 2)) * K   + sw0;
  const u16* Bg1 = Wt + (size_t)(bcol + (s1 >> 2)) * K   + sw1;
  const int d0 = s0 << 3, d1 = s1 << 3;

  auto stage = [&](int kb, u16* Al, u16* Bl){
    gload16(Ag0 + kb, Al + d0);
    gload16(Ag1 + kb, Al + d1);
    gload16(Bg0 + kb, Bl + d0);
    gload16(Bg1 + kb, Bl + d1);
  };
  const int swr = ((lq ^ (lr & 3)) << 3);
  auto compute = [&](const u16* Asb, const u16* Bsb){
    bf16x8 af[4], bfr[4];
    #pragma unroll
    for (int mi = 0; mi < 4; mi++)
      af[mi] = *(const bf16x8*)&Asb[(rb + mi * 16 + lr) * 32 + swr];
    #pragma unroll
    for (int ni = 0; ni < 4; ni++)
      bfr[ni] = *(const bf16x8*)&Bsb[(cb + ni * 16 + lr) * 32 + swr];
    #pragma unroll
    for (int mi = 0; mi < 4; mi++)
      #pragma unroll
      for (int ni = 0; ni < 4; ni++)
        acc[mi][ni] = __builtin_amdgcn_mfma_f32_16x16x32_bf16(af[mi], bfr[ni], acc[mi][ni], 0, 0, 0);
  };

  stage(0, As0, Bs0);
  const int half = K >> 6;
  for (int i2 = 0; i2 < half; i2++){
    const int kb = i2 << 6;
    stage(kb + 32, As1, Bs1);
    wbar<4>();                      // wait stage(kb); stage(kb+32) stays in flight
    compute(As0, Bs0);
    bar();                          // release As0/Bs0 for overwrite
    if (i2 + 1 < half){
      stage(kb + 64, As0, Bs0);
      wbar<4>();
    } else {
      wbar<0>();
    }
    compute(As1, Bs1);
    bar();
  }

  #pragma unroll
  for (int mi = 0; mi < 4; mi++)
    #pragma unroll
    for (int ni = 0; ni < 4; ni++)
      #pragma unroll
      for (int rr = 0; rr < 4; rr++){
        int grow = brow + rb + mi * 16 + lq * 4 + rr;
        int gcol = bcol + cb + ni * 16 + lr;
        float v = acc[mi][ni][rr];
        if (bias) v += DEGBIAS ? (float)deg[grow] * bias[gcol] : bias[gcol];
        out[(size_t)grow * ldc + gcol] = (OT)f2bf(v);
      }
}

// ---- pq_gemm: C[128x128] = A[128x128] @ Wt[128x128]^T + bias ----
// Single-shot: both 32KB tiles staged once, ONE vmcnt(0) fence, then 64 MFMA
// with no further barriers. Row stride 128 u16 (256B); slot p of row r holds
// logical 16B-chunk p ^ (r&7) (2-way bank alias on read = free).
__device__ __forceinline__ void pq_gemm(
    const u16* __restrict__ A, const u16* __restrict__ Wt,
    const float* __restrict__ bias, u16* __restrict__ out,
    int bx, int by, u16* __restrict__ sh, int t)
{
  u16* As = sh;             // 16384 u16
  u16* Bs = sh + 16384;     // 16384 u16
  const int brow = by << 7, bcol = bx << 7;
  const int w = t >> 6, lane = t & 63;
  const int rb = (w >> 1) << 6, cb = (w & 1) << 6;
  const int lr = lane & 15, lq = lane >> 4;

  #pragma unroll
  for (int i = 0; i < 8; i++){
    int sg = i * 256 + t;
    int r = sg >> 4, p = sg & 15;
    int l = p ^ (r & 7);
    gload16(A  + (size_t)(brow + r) * 128 + (l << 3), As + sg * 8);
    gload16(Wt + (size_t)(bcol + r) * 128 + (l << 3), Bs + sg * 8);
  }
  wbar<0>();

  f32x4 acc[4][4];
  #pragma unroll
  for (int i = 0; i < 4; i++)
    #pragma unroll
    for (int j = 0; j < 4; j++) acc[i][j] = (f32x4){0.f, 0.f, 0.f, 0.f};

  #pragma unroll
  for (int kb = 0; kb < 4; kb++){
    bf16x8 af[4], bfr[4];
    #pragma unroll
    for (int mi = 0; mi < 4; mi++){
      int row = rb + mi * 16 + lr;
      af[mi] = *(const bf16x8*)&As[(row << 7) + ((((kb << 2) | lq) ^ (row & 7)) << 3)];
    }
    #pragma unroll
    for (int ni = 0; ni < 4; ni++){
      int row = cb + ni * 16 + lr;
      bfr[ni] = *(const bf16x8*)&Bs[(row << 7) + ((((kb << 2) | lq) ^ (row & 7)) << 3)];
    }
    #pragma unroll
    for (int mi = 0; mi < 4; mi++)
      #pragma unroll
      for (int ni = 0; ni < 4; ni++)
        acc[mi][ni] = __builtin_amdgcn_mfma_f32_16x16x32_bf16(af[mi], bfr[ni], acc[mi][ni], 0, 0, 0);
  }

  #pragma unroll
  for (int mi = 0; mi < 4; mi++)
    #pragma unroll
    for (int ni = 0; ni < 4; ni++)
      #pragma unroll
      for (int rr = 0; rr < 4; rr++){
        int grow = brow + rb + mi * 16 + lq * 4 + rr;
        int gcol = bcol + cb + ni * 16 + lr;
        out[(size_t)grow * 1024 + gcol] = f2bf(acc[mi][ni][rr] + bias[gcol]);
      }
}

// ---- pre_k: weights | cast x | transpose x | histogram ----
__global__ __launch_bounds__(256)
void pre_k(const float* __restrict__ mW1, const float* __restrict__ mb1,
           const float* __restrict__ mW2, const float* __restrict__ uW1,
           const float* __restrict__ uW2, const float* __restrict__ uW3,
           const float* __restrict__ x1, const float* __restrict__ x2,
           const int* __restrict__ ei1, const int* __restrict__ ei2,
           u16* __restrict__ WtPQ, float* __restrict__ bPQ,
           u16* __restrict__ Wtm2, u16* __restrict__ Wtu1,
           u16* __restrict__ Wtu2, u16* __restrict__ Wtu3,
           u16* __restrict__ xb, u16* __restrict__ xt,
           u16* __restrict__ U, int* __restrict__ deg)
{
  __shared__ u16 T[8704];     // 64*136, transpose branch only
  int b = blockIdx.x, t = threadIdx.x;
  if (b < 2692){
    // weight prep
    if (b < 512){                       // WtPQ [1024][128]
      int idx = b * 256 + t; int c = idx >> 7, k = idx & 127;
      int row = (c < 512) ? k : 128 + k;
      WtPQ[idx] = f2bf(mW1[(size_t)row * 512 + (c & 511)]);
    } else if (b < 1024){               // Wtm2 [256][512]
      int idx = (b - 512) * 256 + t; int c = idx >> 9, k = idx & 511;
      Wtm2[idx] = f2bf(mW2[(size_t)k * 256 + c]);
    } else if (b < 2048){               // Wtu1 [512][512]
      int idx = (b - 1024) * 256 + t; int c = idx >> 9, k = idx & 511;
      Wtu1[idx] = f2bf(uW1[(size_t)k * 512 + c]);
    } else if (b < 2560){               // Wtu2 [256][512]
      int idx = (b - 2048) * 256 + t; int c = idx >> 9, k = idx & 511;
      Wtu2[idx] = f2bf(uW2[(size_t)k * 256 + c]);
    } else if (b < 2688){               // Wtu3 [128][256]
      int idx = (b - 2560) * 256 + t; int c = idx >> 8, k = idx & 255;
      Wtu3[idx] = f2bf(uW3[(size_t)k * 128 + c]);
    } else {                            // bPQ [1024]
      int idx = (b - 2688) * 256 + t;
      bPQ[idx] = (idx < 512) ? 0.f : mb1[idx - 512];
    }
  } else if (b < 4740){
    // cast x -> xb + U x-columns (float4 vectorized)
    int a = b - 2692;
    int side = a >> 10, blk = a & 1023;
    const float* x = side ? x2 : x1;
    int i4 = blk * 256 + t;                 // float4 index within side
    float4 v = *(const float4*)&x[(size_t)i4 * 4];
    uint2 pk;
    pk.x = (uint32_t)f2bf(v.x) | ((uint32_t)f2bf(v.y) << 16);
    pk.y = (uint32_t)f2bf(v.z) | ((uint32_t)f2bf(v.w) << 16);
    *(uint2*)&xb[(size_t)side * NN * DD + (size_t)i4 * 4] = pk;
    int n = i4 >> 5, d = (i4 << 2) & 127;
    *(uint2*)&U[((size_t)side * NN + n) * 512 + 384 + d] = pk;
  } else if (b < 4996){
    // transpose: xt[side][d][n] = bf16(x[side][n][d]), 64-node tile
    int a = b - 4740;
    int side = a >> 7, blk = a & 127;
    const float* x = side ? x2 : x1;
    u16* dst = xt + (size_t)side * DD * NN;
    const int n0 = blk * 64;
    #pragma unroll
    for (int i = 0; i < 8; i++){
      int s = i * 256 + t;
      int r = s >> 5, c4 = (s & 31) << 2;
      float4 v = *(const float4*)&x[(size_t)(n0 + r) * DD + c4];
      uint2 pk;
      pk.x = (uint32_t)f2bf(v.x) | ((uint32_t)f2bf(v.y) << 16);
      pk.y = (uint32_t)f2bf(v.z) | ((uint32_t)f2bf(v.w) << 16);
      *(uint2*)&T[r * 136 + c4] = pk;
    }
    __syncthreads();
    #pragma unroll
    for (int i = 0; i < 8; i++){
      int s = i * 256 + t;
      int d = s >> 4, n4 = (s & 15) << 2;
      uint32_t a0 = T[(n4 + 0) * 136 + d];
      uint32_t a1 = T[(n4 + 1) * 136 + d];
      uint32_t a2 = T[(n4 + 2) * 136 + d];
      uint32_t a3 = T[(n4 + 3) * 136 + d];
      uint2 pk; pk.x = a0 | (a1 << 16); pk.y = a2 | (a3 << 16);
      *(uint2*)(dst + (size_t)d * NN + n0 + n4) = pk;
    }
  } else {
    // histogram
    int a = b - 4996;
    int side = a >> 9, blk = a & 511;
    const int* ei = side ? ei2 : ei1;
    int e = blk * 256 + t;
    atomicAdd(&deg[side * NN + ei[e]], 1);
  }
}

// ---- exclusive prefix scan over NN=8192 ints; one block per side ----
__global__ __launch_bounds__(256)
void scan_k(const int* __restrict__ deg,
            int* __restrict__ offs1, int* __restrict__ cur1,
            int* __restrict__ offs2, int* __restrict__ cur2){
  const int* d = deg + blockIdx.x * NN;
  int* offs = blockIdx.x ? offs2 : offs1;
  int* cur  = blockIdx.x ? cur2  : cur1;
  __shared__ int part[256];
  const int t = threadIdx.x;
  const int base = t * 32;
  int loc[32];
  int s = 0;
  #pragma unroll
  for (int i = 0; i < 32; i++){ loc[i] = s; s += d[base + i]; }
  part[t] = s;
  __syncthreads();
  for (int off = 1; off < 256; off <<= 1){
    int v = (t >= off) ? part[t - off] : 0;
    __syncthreads();
    part[t] += v;
    __syncthreads();
  }
  int pre = (t == 0) ? 0 : part[t - 1];
  #pragma unroll
  for (int i = 0; i < 32; i++){
    int o = pre + loc[i];
    offs[base + i] = o;
    cur[base + i]  = o;
  }
  if (t == 255) offs[NN] = part[255];
}

// ---- mid_k: PQ GEMM (single-shot) | scatter edges | cross-attention ----
__global__ __launch_bounds__(256)
void mid_k(const u16* __restrict__ xb, const u16* __restrict__ WtPQ,
           const float* __restrict__ bPQ, u16* __restrict__ PQ,
           const int* __restrict__ ei1, const int* __restrict__ ei2,
           int* __restrict__ cur1, int* __restrict__ cur2,
           int* __restrict__ srt1, int* __restrict__ srt2,
           const u16* __restrict__ xt, u16* __restrict__ U)
{
  __shared__ u16 sh[32768];   // pq: 64KB; attn: XaS 8704 + XbS 17408 = 52KB
  const int b = blockIdx.x, t = threadIdx.x;
  if (b < 1024){
    pq_gemm(xb, WtPQ, bPQ, PQ, b >> 7, b & 127, sh, t);
    return;
  }
  if (b < 2048){
    int a = b - 1024;
    int side = a >> 9, blk = a & 511;
    const int* ei = side ? ei2 : ei1;
    int* cur = side ? cur2 : cur1;
    int* srt = side ? srt2 : srt1;
    int e = blk * 256 + t;
    int tgt = ei[e], src = ei[EE + e];
    int p = atomicAdd(&cur[tgt], 1);
    srt[p] = src;
    return;
  }
  // ---- block-diagonal cross-attention (depends only on pre_k) ----
  const int a = b - 2048;
  const int side = a >> 7;
  const int g = a & 63, h = (a >> 6) & 1;
  const u16* Xa = xb + (size_t)side * NN * DD;
  const u16* Xb = xb + (size_t)(1 - side) * NN * DD;
  const u16* Xt = xt + (size_t)(1 - side) * DD * NN;
  u16* Uside = U + (size_t)side * NN * 512;

  u16* XaS = sh;            // 64*136
  u16* XbS = sh + 8704;     // 128*136

  const int w = t >> 6, lane = t & 63;
  const int lr = lane & 15, lq = lane >> 4;

  {
    const u16* sa = Xa + ((size_t)g * GS + h * 64) * DD;
    #pragma unroll
    for (int i = 0; i < 4; i++){
      int s = i * 256 + t; int r = s >> 4, c8 = (s & 15) << 3;
      *(uint4*)&XaS[r * 136 + c8] = *(const uint4*)(sa + (size_t)r * DD + c8);
    }
    const u16* sb = Xb + (size_t)g * GS * DD;
    #pragma unroll
    for (int i = 0; i < 8; i++){
      int s = i * 256 + t; int r = s >> 4, c8 = (s & 15) << 3;
      *(uint4*)&XbS[r * 136 + c8] = *(const uint4*)(sb + (size_t)r * DD + c8);
    }
  }
  __syncthreads();

  f32x4 sc[8];
  #pragma unroll
  for (int ct = 0; ct < 8; ct++) sc[ct] = (f32x4){0.f, 0.f, 0.f, 0.f};
  #pragma unroll
  for (int kb = 0; kb < 4; kb++){
    bf16x8 aa = *(const bf16x8*)&XaS[(w * 16 + lr) * 136 + kb * 32 + (lq << 3)];
    #pragma unroll
    for (int ct = 0; ct < 8; ct++){
      bf16x8 bb = *(const bf16x8*)&XbS[(ct * 16 + lr) * 136 + kb * 32 + (lq << 3)];
      sc[ct] = __builtin_amdgcn_mfma_f32_16x16x32_bf16(aa, bb, sc[ct], 0, 0, 0);
    }
  }
  float inv[4];
  #pragma unroll
  for (int rr = 0; rr < 4; rr++){
    float m = sc[0][rr];
    #pragma unroll
    for (int ct = 1; ct < 8; ct++) m = fmaxf(m, sc[ct][rr]);
    #pragma unroll
    for (int sh_ = 1; sh_ < 16; sh_ <<= 1) m = fmaxf(m, __shfl_xor(m, sh_, 64));
    float s = 0.f;
    #pragma unroll
    for (int ct = 0; ct < 8; ct++){
      float e = __expf(sc[ct][rr] - m);
      sc[ct][rr] = e; s += e;
    }
    #pragma unroll
    for (int sh_ = 1; sh_ < 16; sh_ <<= 1) s += __shfl_xor(s, sh_, 64);
    inv[rr] = 1.f / s;
  }
  #pragma unroll
  for (int ct = 0; ct < 8; ct++)
    #pragma unroll
    for (int rr = 0; rr < 4; rr++)
      XaS[(w * 16 + lq * 4 + rr) * 136 + ct * 16 + lr] = f2bf(sc[ct][rr] * inv[rr]);
  __syncthreads();

  f32x4 o[8];
  #pragma unroll
  for (int ct = 0; ct < 8; ct++) o[ct] = (f32x4){0.f, 0.f, 0.f, 0.f};
  #pragma unroll
  for (int kb = 0; kb < 4; kb++){
    bf16x8 aa = *(const bf16x8*)&XaS[(w * 16 + lr) * 136 + kb * 32 + (lq << 3)];
    #pragma unroll
    for (int ct = 0; ct < 8; ct++){
      bf16x8 bb = *(const bf16x8*)(Xt + (size_t)(ct * 16 + lr) * NN + g * GS + kb * 32 + (lq << 3));
      o[ct] = __builtin_amdgcn_mfma_f32_16x16x32_bf16(aa, bb, o[ct], 0, 0, 0);
    }
  }
  const u16* XaG = Xa + ((size_t)g * GS + h * 64) * DD;
  #pragma unroll
  for (int ct = 0; ct < 8; ct++)
    #pragma unroll
    for (int rr = 0; rr < 4; rr++){
      int row = w * 16 + lq * 4 + rr, col = ct * 16 + lr;
      float xa = bf2f(XaG[(size_t)row * DD + col]);
      Uside[((size_t)g * GS + h * 64 + row) * 512 + 256 + col] = f2bf(xa - o[ct][rr]);
    }
}

// ---- gather: S[n] = sum relu(P[src]+Q[n]); 1 wave = 1 node; 8/4/1 tiers ----
__global__ __launch_bounds__(256)
void gather_k(const int* __restrict__ offs1, const int* __restrict__ srt1,
              const int* __restrict__ offs2, const int* __restrict__ srt2,
              const u16* __restrict__ PQ, u16* __restrict__ S)
{
  const int side = blockIdx.y;
  const int* offs = side ? offs2 : offs1;
  const int* srt  = side ? srt2  : srt1;
  const u16* base = PQ + (size_t)side * NN * 1024;
  u16* Sb = S + (size_t)side * NN * 512;

  const int node = (blockIdx.x << 2) + (threadIdx.x >> 6);
  const int lane = threadIdx.x & 63;
  const int beg = offs[node], end = offs[node + 1];

  uint4 qv = *(const uint4*)(base + (size_t)node * 1024 + 512 + (lane << 3));
  float q[8];
  {
    uint32_t qw[4] = {qv.x, qv.y, qv.z, qv.w};
    #pragma unroll
    for (int i = 0; i < 4; i++){
      q[i * 2]     = bf2f((u16)(qw[i] & 0xffffu));
      q[i * 2 + 1] = bf2f((u16)(qw[i] >> 16));
    }
  }
  float acc[8] = {0.f,0.f,0.f,0.f,0.f,0.f,0.f,0.f};

  int e = beg;
  for (; e + 7 < end; e += 8){
    int sx[8];
    #pragma unroll
    for (int i = 0; i < 8; i++) sx[i] = srt[e + i];
    uint4 pv[8];
    #pragma unroll
    for (int i = 0; i < 8; i++)
      pv[i] = *(const uint4*)(base + (size_t)sx[i] * 1024 + (lane << 3));
    #pragma unroll
    for (int i = 0; i < 8; i++){
      uint32_t w0[4] = {pv[i].x, pv[i].y, pv[i].z, pv[i].w};
      #pragma unroll
      for (int j = 0; j < 4; j++){
        acc[j*2]   += fmaxf(bf2f((u16)(w0[j] & 0xffffu)) + q[j*2],   0.f);
        acc[j*2+1] += fmaxf(bf2f((u16)(w0[j] >> 16))     + q[j*2+1], 0.f);
      }
    }
  }
  for (; e + 3 < end; e += 4){
    int sx[4];
    #pragma unroll
    for (int i = 0; i < 4; i++) sx[i] = srt[e + i];
    uint4 pv[4];
    #pragma unroll
    for (int i = 0; i < 4; i++)
      pv[i] = *(const uint4*)(base + (size_t)sx[i] * 1024 + (lane << 3));
    #pragma unroll
    for (int i = 0; i < 4; i++){
      uint32_t w0[4] = {pv[i].x, pv[i].y, pv[i].z, pv[i].w};
      #pragma unroll
      for (int j = 0; j < 4; j++){
        acc[j*2]   += fmaxf(bf2f((u16)(w0[j] & 0xffffu)) + q[j*2],   0.f);
        acc[j*2+1] += fmaxf(bf2f((u16)(w0[j] >> 16))     + q[j*2+1], 0.f);
      }
    }
  }
  for (; e < end; e++){
    int sA = srt[e];
    uint4 pA = *(const uint4*)(base + (size_t)sA * 1024 + (lane << 3));
    uint32_t aw[4] = {pA.x, pA.y, pA.z, pA.w};
    #pragma unroll
    for (int i = 0; i < 4; i++){
      acc[i*2]   += fmaxf(bf2f((u16)(aw[i] & 0xffffu)) + q[i*2],   0.f);
      acc[i*2+1] += fmaxf(bf2f((u16)(aw[i] >> 16))     + q[i*2+1], 0.f);
    }
  }
  uint4 pk;
  pk.x = (uint32_t)f2bf(acc[0]) | ((uint32_t)f2bf(acc[1]) << 16);
  pk.y = (uint32_t)f2bf(acc[2]) | ((uint32_t)f2bf(acc[3]) << 16);
  pk.z = (uint32_t)f2bf(acc[4]) | ((uint32_t)f2bf(acc[5]) << 16);
  pk.w = (uint32_t)f2bf(acc[6]) | ((uint32_t)f2bf(acc[7]) << 16);
  *(uint4*)(Sb + (size_t)node * 512 + (lane << 3)) = pk;
}

// ---- msg_k: msg = S @ Wtm2^T + deg*mb2 -> U cols 0..255 ----
__global__ __launch_bounds__(256)
void msg_k(const u16* __restrict__ S, const u16* __restrict__ Wtm2,
           const float* __restrict__ mb2, const int* __restrict__ deg,
           u16* __restrict__ U)
{
  __shared__ u16 sh[16384];
  gemm_body<true,u16>(S, 512, Wtm2, mb2, deg,
                      U, 512, 512, blockIdx.x >> 7, blockIdx.x & 127,
                      sh, threadIdx.x);
}

// ---- upd_k: fused update net. 64 rows/block, 512 threads (2x4 wave grid).
// H1 [64][520], H2 [64][264] in LDS; B weights streamed counted-vmcnt;
// G1's A operand loads straight to registers from global (L2-hot, 4x reuse).
__global__ __launch_bounds__(512)
void upd_k(const u16* __restrict__ U,
           const u16* __restrict__ Wtu1, const float* __restrict__ ub1,
           const u16* __restrict__ Wtu2, const float* __restrict__ ub2,
           const u16* __restrict__ Wtu3, const float* __restrict__ ub3,
           const float* __restrict__ x1, const float* __restrict__ x2,
           float* __restrict__ out)
{
  __shared__ u16 sh[66560];   // 133120 B
  u16* H1s  = sh;             // 64*520 = 33280
  u16* H2s  = sh + 33280;     // 64*264 = 16896
  u16* Bst0 = sh + 50176;     // 8192 (1024 slots of 8)
  u16* Bst1 = sh + 58368;     // 8192

  const int t = threadIdx.x;
  const int w = t >> 6, lane = t & 63;
  const int wr = w >> 2, wc = w & 3;     // 2 (rows) x 4 (cols) waves
  const int lr = lane & 15, lq = lane >> 4;
  const int r0 = blockIdx.x << 6;

  const int sB0 = t, sB1 = t + 512;      // B slots
  const int cB0 = sB0 >> 2, cB1 = sB1 >> 2;
  const int swB0 = (((sB0 & 3) ^ (cB0 & 3)) << 3);
  const int swB1 = (((sB1 & 3) ^ (cB1 & 3)) << 3);
  const int swr = ((lq ^ (lr & 3)) << 3);

  f32x4 acc[2][4];
  auto zacc = [&](){
    #pragma unroll
    for (int i = 0; i < 2; i++)
      #pragma unroll
      for (int j = 0; j < 4; j++) acc[i][j] = (f32x4){0.f, 0.f, 0.f, 0.f};
  };

  // ---- G1: H1 = relu(U @ Wtu1^T + b1), K=512, 512 cols in 2 halves ----
  bf16x8 afA[2], afB[2];
  auto ldA = [&](int kb, bf16x8 (&af)[2]){
    #pragma unroll
    for (int mi = 0; mi < 2; mi++)
      af[mi] = *(const bf16x8*)&U[(size_t)(r0 + wr * 32 + mi * 16 + lr) * 512 + kb + (lq << 3)];
  };
  auto compA = [&](const bf16x8 (&af)[2], const u16* Bsb){
    bf16x8 bfv[4];
    #pragma unroll
    for (int ct = 0; ct < 4; ct++)
      bfv[ct] = *(const bf16x8*)&Bsb[(wc * 64 + ct * 16 + lr) * 32 + swr];
    #pragma unroll
    for (int mi = 0; mi < 2; mi++)
      #pragma unroll
      for (int ct = 0; ct < 4; ct++)
        acc[mi][ct] = __builtin_amdgcn_mfma_f32_16x16x32_bf16(af[mi], bfv[ct], acc[mi][ct], 0, 0, 0);
  };
  for (int hN = 0; hN < 2; hN++){
    zacc();
    auto stB = [&](int kb, u16* dst){
      gload16(Wtu1 + (size_t)(hN * 256 + cB0) * 512 + kb + swB0, dst + sB0 * 8);
      gload16(Wtu1 + (size_t)(hN * 256 + cB1) * 512 + kb + swB1, dst + sB1 * 8);
    };
    stB(0, Bst0);
    ldA(0, afA);
    for (int i2 = 0; i2 < 8; i2++){
      const int kb = i2 << 6;
      stB(kb + 32, Bst1); ldA(kb + 32, afB);
      wbar<4>();                     // waits stB(kb)+ldA(kb); newer 4 in flight
      compA(afA, Bst0);
      bar();
      if (i2 < 7){
        stB(kb + 64, Bst0); ldA(kb + 64, afA);
        wbar<4>();
      } else {
        wbar<0>();
      }
      compA(afB, Bst1);
      bar();
    }
    #pragma unroll
    for (int mi = 0; mi < 2; mi++)
      #pragma unroll
      for (int ct = 0; ct < 4; ct++)
        #pragma unroll
        for (int rr = 0; rr < 4; rr++){
          int row = wr * 32 + mi * 16 + lq * 4 + rr;
          int col = wc * 64 + ct * 16 + lr;
          float v = acc[mi][ct][rr] + ub1[hN * 256 + col];
          H1s[row * 520 + hN * 256 + col] = f2bf(fmaxf(v, 0.f));
        }
  }
  __syncthreads();

  // ---- G2: H2 = relu(H1 @ Wtu2^T + b2), K=512, 256 cols ----
  zacc();
  {
    auto stB = [&](int kb, u16* dst){
      gload16(Wtu2 + (size_t)cB0 * 512 + kb + swB0, dst + sB0 * 8);
      gload16(Wtu2 + (size_t)cB1 * 512 + kb + swB1, dst + sB1 * 8);
    };
    auto comp = [&](int kb, const u16* Bsb){
      bf16x8 af[2], bfv[4];
      #pragma unroll
      for (int mi = 0; mi < 2; mi++)
        af[mi] = *(const bf16x8*)&H1s[(wr * 32 + mi * 16 + lr) * 520 + kb + (lq << 3)];
      #pragma unroll
      for (int ct = 0; ct < 4; ct++)
        bfv[ct] = *(const bf16x8*)&Bsb[(wc * 64 + ct * 16 + lr) * 32 + swr];
      #pragma unroll
      for (int mi = 0; mi < 2; mi++)
        #pragma unroll
        for (int ct = 0; ct < 4; ct++)
          acc[mi][ct] = __builtin_amdgcn_mfma_f32_16x16x32_bf16(af[mi], bfv[ct], acc[mi][ct], 0, 0, 0);
    };
    stB(0, Bst0);
    for (int i2 = 0; i2 < 8; i2++){
      const int kb = i2 << 6;
      stB(kb + 32, Bst1);
      wbar<2>();
      comp(kb, Bst0);
      bar();
      if (i2 < 7){
        stB(kb + 64, Bst0);
        wbar<2>();
      } else {
        wbar<0>();
      }
      comp(kb + 32, Bst1);
      bar();
    }
    #pragma unroll
    for (int mi = 0; mi < 2; mi++)
      #pragma unroll
      for (int ct = 0; ct < 4; ct++)
        #pragma unroll
        for (int rr = 0; rr < 4; rr++){
          int row = wr * 32 + mi * 16 + lq * 4 + rr;
          int col = wc * 64 + ct * 16 + lr;
          H2s[row * 264 + col] = f2bf(fmaxf(acc[mi][ct][rr] + ub2[col], 0.f));
        }
  }
  __syncthreads();

  // ---- G3: out = x + H2 @ Wtu3^T + b3, K=256, 128 cols ----
  zacc();
  {
    auto stB = [&](int kb, u16* dst){
      gload16(Wtu3 + (size_t)cB0 * 256 + kb + swB0, dst + sB0 * 8);   // 512 slots
    };
    auto comp = [&](int kb, const u16* Bsb){
      bf16x8 af[2], bfv[2];
      #pragma unroll
      for (int mi = 0; mi < 2; mi++)
        af[mi] = *(const bf16x8*)&H2s[(wr * 32 + mi * 16 + lr) * 264 + kb + (lq << 3)];
      #pragma unroll
      for (int ct = 0; ct < 2; ct++)
        bfv[ct] = *(const bf16x8*)&Bsb[(wc * 32 + ct * 16 + lr) * 32 + swr];
      #pragma unroll
      for (int mi = 0; mi < 2; mi++)
        #pragma unroll
        for (int ct = 0; ct < 2; ct++)
          acc[mi][ct] = __builtin_amdgcn_mfma_f32_16x16x32_bf16(af[mi], bfv[ct], acc[mi][ct], 0, 0, 0);
    };
    stB(0, Bst0);
    for (int i2 = 0; i2 < 4; i2++){
      const int kb = i2 << 6;
      stB(kb + 32, Bst1);
      wbar<1>();
      comp(kb, Bst0);
      bar();
      if (i2 < 3){
        stB(kb + 64, Bst0);
        wbar<1>();
      } else {
        wbar<0>();
      }
      comp(kb + 32, Bst1);
      bar();
    }
    #pragma unroll
    for (int mi = 0; mi < 2; mi++)
      #pragma unroll
      for (int ct = 0; ct < 2; ct++)
        #pragma unroll
        for (int rr = 0; rr < 4; rr++){
          int row = wr * 32 + mi * 16 + lq * 4 + rr;
          int col = wc * 32 + ct * 16 + lr;
          int grow = r0 + row;
          const float* rp = (grow < NN) ? x1 : x2;
          float v = acc[mi][ct][rr] + ub3[col]
                  + rp[(size_t)(grow & (NN - 1)) * 128 + col];
          out[(size_t)grow * 128 + col] = v;
        }
  }
}

extern "C" void kernel_launch(void* const* d_in, const int* in_sizes, int n_in,
                              void* d_out, int out_size, void* d_ws, size_t ws_size,
                              hipStream_t stream)
{
  const float* x1  = (const float*)d_in[0];
  const int*   ei1 = (const int*)  d_in[1];
  const float* x2  = (const float*)d_in[3];
  const int*   ei2 = (const int*)  d_in[4];
  const float* mW1 = (const float*)d_in[6];
  const float* mb1 = (const float*)d_in[7];
  const float* mW2 = (const float*)d_in[8];
  const float* mb2 = (const float*)d_in[9];
  const float* uW1 = (const float*)d_in[10];
  const float* ub1 = (const float*)d_in[11];
  const float* uW2 = (const float*)d_in[12];
  const float* ub2 = (const float*)d_in[13];
  const float* uW3 = (const float*)d_in[14];
  const float* ub3 = (const float*)d_in[15];
  float* out = (float*)d_out;

  char* w = (char*)d_ws;
  auto alloc = [&](size_t b){ char* p = w; w += (b + 255) & ~(size_t)255; return p; };
  u16*  S    = (u16*)alloc((size_t)2 * NN * 512 * 2);
  u16*  PQ   = (u16*)alloc((size_t)2 * NN * 1024 * 2);
  u16*  xb   = (u16*)alloc((size_t)2 * NN * DD * 2);
  u16*  xt   = (u16*)alloc((size_t)2 * DD * NN * 2);
  u16*  U    = (u16*)alloc((size_t)2 * NN * 512 * 2);
  int*  deg  = (int*)alloc((size_t)2 * NN * 4);
  int*  offs1 = (int*)alloc((NN + 1) * 4);
  int*  offs2 = (int*)alloc((NN + 1) * 4);
  int*  cur1  = (int*)alloc(NN * 4);
  int*  cur2  = (int*)alloc(NN * 4);
  int*  srt1  = (int*)alloc((size_t)EE * 4);
  int*  srt2  = (int*)alloc((size_t)EE * 4);
  u16*  WtPQ = (u16*)alloc(1024 * 128 * 2);
  float* bPQ = (float*)alloc(1024 * 4);
  u16*  Wtm2 = (u16*)alloc(256 * 512 * 2);
  u16*  Wtu1 = (u16*)alloc(512 * 512 * 2);
  u16*  Wtu2 = (u16*)alloc(256 * 512 * 2);
  u16*  Wtu3 = (u16*)alloc(128 * 256 * 2);

  hipMemsetAsync(deg, 0, (size_t)2 * NN * 4, stream);

  pre_k<<<4996 + 1024, 256, 0, stream>>>(
      mW1, mb1, mW2, uW1, uW2, uW3, x1, x2, ei1, ei2,
      WtPQ, bPQ, Wtm2, Wtu1, Wtu2, Wtu3, xb, xt, U, deg);

  scan_k<<<2, 256, 0, stream>>>(deg, offs1, cur1, offs2, cur2);

  mid_k<<<2304, 256, 0, stream>>>(xb, WtPQ, bPQ, PQ, ei1, ei2,
                                  cur1, cur2, srt1, srt2, xt, U);

  gather_k<<<dim3(NN / 4, 2), 256, 0, stream>>>(offs1, srt1, offs2, srt2, PQ, S);

  msg_k<<<256, 256, 0, stream>>>(S, Wtm2, mb2, deg, U);

  upd_k<<<256, 512, 0, stream>>>(U, Wtu1, ub1, Wtu2, ub2, Wtu3, ub3,
                                 x1, x2, out);
}

// Round 9
// 220.224 us; speedup vs baseline: 1.4411x; 1.0399x over previous
//
#include <hip/hip_runtime.h>
#include <stdint.h>

// GMNConv R14 = R13 with:
//  (a) attn moved BACK into the msg dispatch (R11 form): R13's attn-in-mid_k
//      left msg_k alone at 1 block/CU with no overlap partner (+7us). mid_k
//      reverts to pq_gemm | scatter.
//  (b) pre_k weight prep rewritten as LDS-tiled 64x64 transposes: the old
//      per-element form read the f32 sources at 1-2KB stride (16x overfetch,
//      ~50MB effective). Now coalesced float4 reads -> LDS -> coalesced
//      uint2 writes. 168 tile blocks replace 2688 scalar blocks.
//  (c) gather_k gains a 16-deep unroll tier (was 8 max): doubles per-wave
//      in-flight bytes on the latency-bound random P-row reads.
//  pre_k    : weight transpose (tiled) + bPQ + x cast (+U x-cols) + x transpose + histogram
//  scan_k   : exclusive prefix scan of deg -> offs/cur
//  mid_k    : PQ = xb@WtPQ^T + bPQ (single-shot MFMA) || scatter
//  gather_k : S[n] = sum relu(P[src]+Q[n])  (16/8/4/1 unroll)
//  msgattn_k: msg = S@mW2 + deg*mb2 (MFMA) || block-diag cross-attention
//  upd_k    : H1 = relu(U@uW1+b1) [LDS]; H2 = relu(H1@uW2+b2) [LDS];
//             out = x + H2@uW3+b3

typedef unsigned short u16;
typedef __bf16 bf16x8 __attribute__((ext_vector_type(8)));
typedef float f32x4 __attribute__((ext_vector_type(4)));

#define NN 8192
#define DD 128
#define EE 131072
#define GS 128
#define NG 64

__device__ __forceinline__ float bf2f(u16 u){
  return __uint_as_float(((uint32_t)u) << 16);
}
__device__ __forceinline__ u16 f2bf(float f){
  uint32_t x = __float_as_uint(f);
  return (u16)((x + 0x7fffu + ((x >> 16) & 1u)) >> 16);
}
__device__ __forceinline__ void gload16(const u16* g, u16* l){
  __builtin_amdgcn_global_load_lds(
      (const __attribute__((address_space(1))) uint32_t*)(uintptr_t)g,
      (__attribute__((address_space(3))) uint32_t*)(uintptr_t)l, 16, 0, 0);
}
// counted-vmcnt fence + barrier (T4: N>0 keeps newer loads in flight)
template<int N>
__device__ __forceinline__ void wbar(){
  if constexpr (N == 0)      asm volatile("s_waitcnt vmcnt(0)" ::: "memory");
  else if constexpr (N == 1) asm volatile("s_waitcnt vmcnt(1)" ::: "memory");
  else if constexpr (N == 2) asm volatile("s_waitcnt vmcnt(2)" ::: "memory");
  else if constexpr (N == 4) asm volatile("s_waitcnt vmcnt(4)" ::: "memory");
  __builtin_amdgcn_s_barrier();
  __builtin_amdgcn_sched_barrier(0);
}
__device__ __forceinline__ void bar(){
  __builtin_amdgcn_s_barrier();
  __builtin_amdgcn_sched_barrier(0);
}

// ---- gemm_body: C[128x128 tile] = A@Wt^T + bias (msg GEMM) ----
// Wt [Nc][K] row-major bf16; BK=32; counted-vmcnt 2-phase; K multiple of 64.
// LDS: physical 16B-slot p of row r holds logical K-chunk p ^ (r&3).
template<bool DEGBIAS, typename OT>
__device__ __forceinline__ void gemm_body(
    const u16* __restrict__ A, int lda,
    const u16* __restrict__ Wt, const float* __restrict__ bias,
    const int* __restrict__ deg,
    OT* __restrict__ out, int ldc, int K, int bx, int by,
    u16* __restrict__ sh, int t)
{
  u16* As0 = sh;         u16* Bs0 = sh + 4096;
  u16* As1 = sh + 8192;  u16* Bs1 = sh + 12288;
  const int brow = by << 7, bcol = bx << 7;
  const int w = t >> 6, lane = t & 63;
  const int rb = (w >> 1) << 6, cb = (w & 1) << 6;
  const int lr = lane & 15, lq = lane >> 4;

  f32x4 acc[4][4];
  #pragma unroll
  for (int i = 0; i < 4; i++)
    #pragma unroll
    for (int j = 0; j < 4; j++) acc[i][j] = (f32x4){0.f, 0.f, 0.f, 0.f};

  const int s0 = t, s1 = t + 256;
  const int sw0 = (((s0 & 3) ^ ((s0 >> 2) & 3)) << 3);
  const int sw1 = (((s1 & 3) ^ ((s1 >> 2) & 3)) << 3);
  const u16* Ag0 = A  + (size_t)(brow + (s0 >> 2)) * lda + sw0;
  const u16* Ag1 = A  + (size_t)(brow + (s1 >> 2)) * lda + sw1;
  const u16* Bg0 = Wt + (size_t)(bcol + (s0 >> 2)) * K   + sw0;
  const u16* Bg1 = Wt + (size_t)(bcol + (s1 >> 2)) * K   + sw1;
  const int d0 = s0 << 3, d1 = s1 << 3;

  auto stage = [&](int kb, u16* Al, u16* Bl){
    gload16(Ag0 + kb, Al + d0);
    gload16(Ag1 + kb, Al + d1);
    gload16(Bg0 + kb, Bl + d0);
    gload16(Bg1 + kb, Bl + d1);
  };
  const int swr = ((lq ^ (lr & 3)) << 3);
  auto compute = [&](const u16* Asb, const u16* Bsb){
    bf16x8 af[4], bfr[4];
    #pragma unroll
    for (int mi = 0; mi < 4; mi++)
      af[mi] = *(const bf16x8*)&Asb[(rb + mi * 16 + lr) * 32 + swr];
    #pragma unroll
    for (int ni = 0; ni < 4; ni++)
      bfr[ni] = *(const bf16x8*)&Bsb[(cb + ni * 16 + lr) * 32 + swr];
    #pragma unroll
    for (int mi = 0; mi < 4; mi++)
      #pragma unroll
      for (int ni = 0; ni < 4; ni++)
        acc[mi][ni] = __builtin_amdgcn_mfma_f32_16x16x32_bf16(af[mi], bfr[ni], acc[mi][ni], 0, 0, 0);
  };

  stage(0, As0, Bs0);
  const int half = K >> 6;
  for (int i2 = 0; i2 < half; i2++){
    const int kb = i2 << 6;
    stage(kb + 32, As1, Bs1);
    wbar<4>();                      // wait stage(kb); stage(kb+32) stays in flight
    compute(As0, Bs0);
    bar();                          // release As0/Bs0 for overwrite
    if (i2 + 1 < half){
      stage(kb + 64, As0, Bs0);
      wbar<4>();
    } else {
      wbar<0>();
    }
    compute(As1, Bs1);
    bar();
  }

  #pragma unroll
  for (int mi = 0; mi < 4; mi++)
    #pragma unroll
    for (int ni = 0; ni < 4; ni++)
      #pragma unroll
      for (int rr = 0; rr < 4; rr++){
        int grow = brow + rb + mi * 16 + lq * 4 + rr;
        int gcol = bcol + cb + ni * 16 + lr;
        float v = acc[mi][ni][rr];
        if (bias) v += DEGBIAS ? (float)deg[grow] * bias[gcol] : bias[gcol];
        out[(size_t)grow * ldc + gcol] = (OT)f2bf(v);
      }
}

// ---- pq_gemm: C[128x128] = A[128x128] @ Wt[128x128]^T + bias ----
// Single-shot: both 32KB tiles staged once, ONE vmcnt(0) fence, then 64 MFMA
// with no further barriers. Row stride 128 u16 (256B); slot p of row r holds
// logical 16B-chunk p ^ (r&7) (2-way bank alias on read = free).
__device__ __forceinline__ void pq_gemm(
    const u16* __restrict__ A, const u16* __restrict__ Wt,
    const float* __restrict__ bias, u16* __restrict__ out,
    int bx, int by, u16* __restrict__ sh, int t)
{
  u16* As = sh;             // 16384 u16
  u16* Bs = sh + 16384;     // 16384 u16
  const int brow = by << 7, bcol = bx << 7;
  const int w = t >> 6, lane = t & 63;
  const int rb = (w >> 1) << 6, cb = (w & 1) << 6;
  const int lr = lane & 15, lq = lane >> 4;

  #pragma unroll
  for (int i = 0; i < 8; i++){
    int sg = i * 256 + t;
    int r = sg >> 4, p = sg & 15;
    int l = p ^ (r & 7);
    gload16(A  + (size_t)(brow + r) * 128 + (l << 3), As + sg * 8);
    gload16(Wt + (size_t)(bcol + r) * 128 + (l << 3), Bs + sg * 8);
  }
  wbar<0>();

  f32x4 acc[4][4];
  #pragma unroll
  for (int i = 0; i < 4; i++)
    #pragma unroll
    for (int j = 0; j < 4; j++) acc[i][j] = (f32x4){0.f, 0.f, 0.f, 0.f};

  #pragma unroll
  for (int kb = 0; kb < 4; kb++){
    bf16x8 af[4], bfr[4];
    #pragma unroll
    for (int mi = 0; mi < 4; mi++){
      int row = rb + mi * 16 + lr;
      af[mi] = *(const bf16x8*)&As[(row << 7) + ((((kb << 2) | lq) ^ (row & 7)) << 3)];
    }
    #pragma unroll
    for (int ni = 0; ni < 4; ni++){
      int row = cb + ni * 16 + lr;
      bfr[ni] = *(const bf16x8*)&Bs[(row << 7) + ((((kb << 2) | lq) ^ (row & 7)) << 3)];
    }
    #pragma unroll
    for (int mi = 0; mi < 4; mi++)
      #pragma unroll
      for (int ni = 0; ni < 4; ni++)
        acc[mi][ni] = __builtin_amdgcn_mfma_f32_16x16x32_bf16(af[mi], bfr[ni], acc[mi][ni], 0, 0, 0);
  }

  #pragma unroll
  for (int mi = 0; mi < 4; mi++)
    #pragma unroll
    for (int ni = 0; ni < 4; ni++)
      #pragma unroll
      for (int rr = 0; rr < 4; rr++){
        int grow = brow + rb + mi * 16 + lq * 4 + rr;
        int gcol = bcol + cb + ni * 16 + lr;
        out[(size_t)grow * 1024 + gcol] = f2bf(acc[mi][ni][rr] + bias[gcol]);
      }
}

// ---- pre_k: tiled weight transpose | bPQ | cast x | transpose x | histogram ----
// Block layout: [0,168) weight 64x64 tiles; 168 bPQ; [169,2217) x cast;
// [2217,2473) x transpose; [2473,3497) histogram.
__global__ __launch_bounds__(256)
void pre_k(const float* __restrict__ mW1, const float* __restrict__ mb1,
           const float* __restrict__ mW2, const float* __restrict__ uW1,
           const float* __restrict__ uW2, const float* __restrict__ uW3,
           const float* __restrict__ x1, const float* __restrict__ x2,
           const int* __restrict__ ei1, const int* __restrict__ ei2,
           u16* __restrict__ WtPQ, float* __restrict__ bPQ,
           u16* __restrict__ Wtm2, u16* __restrict__ Wtu1,
           u16* __restrict__ Wtu2, u16* __restrict__ Wtu3,
           u16* __restrict__ xb, u16* __restrict__ xt,
           u16* __restrict__ U, int* __restrict__ deg)
{
  __shared__ u16 T[8704];     // weight tiles use 64*68=4352; x-transpose 64*136
  int b = blockIdx.x, t = threadIdx.x;
  if (b < 168){
    // one 64x64 tile of dst[c][k] = f2bf(src[k][c])
    // jobs: {src, dst, C(=ldS), K(=ldD), tile-cols}
    const float* srcs[6] = {mW1, mW1 + 128 * 512, mW2, uW1, uW2, uW3};
    u16* dsts[6] = {WtPQ, WtPQ + 512 * 128, Wtm2, Wtu1, Wtu2, Wtu3};
    const int ldSs[6] = {512, 512, 256, 512, 256, 128};
    const int ldDs[6] = {128, 128, 512, 512, 512, 256};
    const int jb[7]   = {0, 16, 32, 64, 128, 160, 168};
    int j = 0;
    while (b >= jb[j + 1]) j++;
    const int l = b - jb[j];
    const int ldS = ldSs[j], ldD = ldDs[j];
    const int ntc = ldS >> 6;              // C/64
    const int k0 = (l / ntc) << 6, c0 = (l % ntc) << 6;
    const float* S = srcs[j];
    u16* D = dsts[j];
    #pragma unroll
    for (int i = 0; i < 4; i++){
      int s = i * 256 + t;
      int r = s >> 4, c4 = (s & 15) << 2;
      float4 v = *(const float4*)&S[(size_t)(k0 + r) * ldS + c0 + c4];
      uint2 pk;
      pk.x = (uint32_t)f2bf(v.x) | ((uint32_t)f2bf(v.y) << 16);
      pk.y = (uint32_t)f2bf(v.z) | ((uint32_t)f2bf(v.w) << 16);
      *(uint2*)&T[r * 68 + c4] = pk;
    }
    __syncthreads();
    #pragma unroll
    for (int i = 0; i < 4; i++){
      int s = i * 256 + t;
      int c = s >> 4, k4 = (s & 15) << 2;
      uint32_t a0 = T[(k4 + 0) * 68 + c];
      uint32_t a1 = T[(k4 + 1) * 68 + c];
      uint32_t a2 = T[(k4 + 2) * 68 + c];
      uint32_t a3 = T[(k4 + 3) * 68 + c];
      uint2 pk; pk.x = a0 | (a1 << 16); pk.y = a2 | (a3 << 16);
      *(uint2*)&D[(size_t)(c0 + c) * ldD + k0 + k4] = pk;
    }
  } else if (b == 168){
    #pragma unroll
    for (int i = 0; i < 4; i++){
      int idx = i * 256 + t;
      bPQ[idx] = (idx < 512) ? 0.f : mb1[idx - 512];
    }
  } else if (b < 2217){
    // cast x -> xb + U x-columns (float4 vectorized)
    int a = b - 169;
    int side = a >> 10, blk = a & 1023;
    const float* x = side ? x2 : x1;
    int i4 = blk * 256 + t;                 // float4 index within side
    float4 v = *(const float4*)&x[(size_t)i4 * 4];
    uint2 pk;
    pk.x = (uint32_t)f2bf(v.x) | ((uint32_t)f2bf(v.y) << 16);
    pk.y = (uint32_t)f2bf(v.z) | ((uint32_t)f2bf(v.w) << 16);
    *(uint2*)&xb[(size_t)side * NN * DD + (size_t)i4 * 4] = pk;
    int n = i4 >> 5, d = (i4 << 2) & 127;
    *(uint2*)&U[((size_t)side * NN + n) * 512 + 384 + d] = pk;
  } else if (b < 2473){
    // transpose: xt[side][d][n] = bf16(x[side][n][d]), 64-node tile
    int a = b - 2217;
    int side = a >> 7, blk = a & 127;
    const float* x = side ? x2 : x1;
    u16* dst = xt + (size_t)side * DD * NN;
    const int n0 = blk * 64;
    #pragma unroll
    for (int i = 0; i < 8; i++){
      int s = i * 256 + t;
      int r = s >> 5, c4 = (s & 31) << 2;
      float4 v = *(const float4*)&x[(size_t)(n0 + r) * DD + c4];
      uint2 pk;
      pk.x = (uint32_t)f2bf(v.x) | ((uint32_t)f2bf(v.y) << 16);
      pk.y = (uint32_t)f2bf(v.z) | ((uint32_t)f2bf(v.w) << 16);
      *(uint2*)&T[r * 136 + c4] = pk;
    }
    __syncthreads();
    #pragma unroll
    for (int i = 0; i < 8; i++){
      int s = i * 256 + t;
      int d = s >> 4, n4 = (s & 15) << 2;
      uint32_t a0 = T[(n4 + 0) * 136 + d];
      uint32_t a1 = T[(n4 + 1) * 136 + d];
      uint32_t a2 = T[(n4 + 2) * 136 + d];
      uint32_t a3 = T[(n4 + 3) * 136 + d];
      uint2 pk; pk.x = a0 | (a1 << 16); pk.y = a2 | (a3 << 16);
      *(uint2*)(dst + (size_t)d * NN + n0 + n4) = pk;
    }
  } else {
    // histogram
    int a = b - 2473;
    int side = a >> 9, blk = a & 511;
    const int* ei = side ? ei2 : ei1;
    int e = blk * 256 + t;
    atomicAdd(&deg[side * NN + ei[e]], 1);
  }
}

// ---- exclusive prefix scan over NN=8192 ints; one block per side ----
__global__ __launch_bounds__(256)
void scan_k(const int* __restrict__ deg,
            int* __restrict__ offs1, int* __restrict__ cur1,
            int* __restrict__ offs2, int* __restrict__ cur2){
  const int* d = deg + blockIdx.x * NN;
  int* offs = blockIdx.x ? offs2 : offs1;
  int* cur  = blockIdx.x ? cur2  : cur1;
  __shared__ int part[256];
  const int t = threadIdx.x;
  const int base = t * 32;
  int loc[32];
  int s = 0;
  #pragma unroll
  for (int i = 0; i < 32; i++){ loc[i] = s; s += d[base + i]; }
  part[t] = s;
  __syncthreads();
  for (int off = 1; off < 256; off <<= 1){
    int v = (t >= off) ? part[t - off] : 0;
    __syncthreads();
    part[t] += v;
    __syncthreads();
  }
  int pre = (t == 0) ? 0 : part[t - 1];
  #pragma unroll
  for (int i = 0; i < 32; i++){
    int o = pre + loc[i];
    offs[base + i] = o;
    cur[base + i]  = o;
  }
  if (t == 255) offs[NN] = part[255];
}

// ---- mid_k: PQ GEMM (single-shot K=128) | scatter edges ----
__global__ __launch_bounds__(256)
void mid_k(const u16* __restrict__ xb, const u16* __restrict__ WtPQ,
           const float* __restrict__ bPQ, u16* __restrict__ PQ,
           const int* __restrict__ ei1, const int* __restrict__ ei2,
           int* __restrict__ cur1, int* __restrict__ cur2,
           int* __restrict__ srt1, int* __restrict__ srt2)
{
  __shared__ u16 sh[32768];   // 64KB: As 32KB + Bs 32KB
  const int b = blockIdx.x, t = threadIdx.x;
  if (b < 1024){
    pq_gemm(xb, WtPQ, bPQ, PQ, b >> 7, b & 127, sh, t);
  } else {
    int a = b - 1024;
    int side = a >> 9, blk = a & 511;
    const int* ei = side ? ei2 : ei1;
    int* cur = side ? cur2 : cur1;
    int* srt = side ? srt2 : srt1;
    int e = blk * 256 + t;
    int tgt = ei[e], src = ei[EE + e];
    int p = atomicAdd(&cur[tgt], 1);
    srt[p] = src;
  }
}

// ---- gather: S[n] = sum relu(P[src]+Q[n]); 1 wave = 1 node; 16/8/4/1 ----
__global__ __launch_bounds__(256)
void gather_k(const int* __restrict__ offs1, const int* __restrict__ srt1,
              const int* __restrict__ offs2, const int* __restrict__ srt2,
              const u16* __restrict__ PQ, u16* __restrict__ S)
{
  const int side = blockIdx.y;
  const int* offs = side ? offs2 : offs1;
  const int* srt  = side ? srt2  : srt1;
  const u16* base = PQ + (size_t)side * NN * 1024;
  u16* Sb = S + (size_t)side * NN * 512;

  const int node = (blockIdx.x << 2) + (threadIdx.x >> 6);
  const int lane = threadIdx.x & 63;
  const int beg = offs[node], end = offs[node + 1];
  const u16* lbase = base + (lane << 3);

  uint4 qv = *(const uint4*)(base + (size_t)node * 1024 + 512 + (lane << 3));
  float q[8];
  {
    uint32_t qw[4] = {qv.x, qv.y, qv.z, qv.w};
    #pragma unroll
    for (int i = 0; i < 4; i++){
      q[i * 2]     = bf2f((u16)(qw[i] & 0xffffu));
      q[i * 2 + 1] = bf2f((u16)(qw[i] >> 16));
    }
  }
  float acc[8] = {0.f,0.f,0.f,0.f,0.f,0.f,0.f,0.f};

  int e = beg;
  for (; e + 15 < end; e += 16){
    int sx[16];
    #pragma unroll
    for (int i = 0; i < 16; i++) sx[i] = srt[e + i];
    uint4 pv[16];
    #pragma unroll
    for (int i = 0; i < 16; i++)
      pv[i] = *(const uint4*)(lbase + (size_t)sx[i] * 1024);
    #pragma unroll
    for (int i = 0; i < 16; i++){
      uint32_t w0[4] = {pv[i].x, pv[i].y, pv[i].z, pv[i].w};
      #pragma unroll
      for (int j = 0; j < 4; j++){
        acc[j*2]   += fmaxf(bf2f((u16)(w0[j] & 0xffffu)) + q[j*2],   0.f);
        acc[j*2+1] += fmaxf(bf2f((u16)(w0[j] >> 16))     + q[j*2+1], 0.f);
      }
    }
  }
  for (; e + 7 < end; e += 8){
    int sx[8];
    #pragma unroll
    for (int i = 0; i < 8; i++) sx[i] = srt[e + i];
    uint4 pv[8];
    #pragma unroll
    for (int i = 0; i < 8; i++)
      pv[i] = *(const uint4*)(lbase + (size_t)sx[i] * 1024);
    #pragma unroll
    for (int i = 0; i < 8; i++){
      uint32_t w0[4] = {pv[i].x, pv[i].y, pv[i].z, pv[i].w};
      #pragma unroll
      for (int j = 0; j < 4; j++){
        acc[j*2]   += fmaxf(bf2f((u16)(w0[j] & 0xffffu)) + q[j*2],   0.f);
        acc[j*2+1] += fmaxf(bf2f((u16)(w0[j] >> 16))     + q[j*2+1], 0.f);
      }
    }
  }
  for (; e + 3 < end; e += 4){
    int sx[4];
    #pragma unroll
    for (int i = 0; i < 4; i++) sx[i] = srt[e + i];
    uint4 pv[4];
    #pragma unroll
    for (int i = 0; i < 4; i++)
      pv[i] = *(const uint4*)(lbase + (size_t)sx[i] * 1024);
    #pragma unroll
    for (int i = 0; i < 4; i++){
      uint32_t w0[4] = {pv[i].x, pv[i].y, pv[i].z, pv[i].w};
      #pragma unroll
      for (int j = 0; j < 4; j++){
        acc[j*2]   += fmaxf(bf2f((u16)(w0[j] & 0xffffu)) + q[j*2],   0.f);
        acc[j*2+1] += fmaxf(bf2f((u16)(w0[j] >> 16))     + q[j*2+1], 0.f);
      }
    }
  }
  for (; e < end; e++){
    int sA = srt[e];
    uint4 pA = *(const uint4*)(lbase + (size_t)sA * 1024);
    uint32_t aw[4] = {pA.x, pA.y, pA.z, pA.w};
    #pragma unroll
    for (int i = 0; i < 4; i++){
      acc[i*2]   += fmaxf(bf2f((u16)(aw[i] & 0xffffu)) + q[i*2],   0.f);
      acc[i*2+1] += fmaxf(bf2f((u16)(aw[i] >> 16))     + q[i*2+1], 0.f);
    }
  }
  uint4 pk;
  pk.x = (uint32_t)f2bf(acc[0]) | ((uint32_t)f2bf(acc[1]) << 16);
  pk.y = (uint32_t)f2bf(acc[2]) | ((uint32_t)f2bf(acc[3]) << 16);
  pk.z = (uint32_t)f2bf(acc[4]) | ((uint32_t)f2bf(acc[5]) << 16);
  pk.w = (uint32_t)f2bf(acc[6]) | ((uint32_t)f2bf(acc[7]) << 16);
  *(uint4*)(Sb + (size_t)node * 512 + (lane << 3)) = pk;
}

// ---- msgattn_k: msg GEMM | MFMA block-diag cross-attention ----
__global__ __launch_bounds__(256)
void msgattn_k(const u16* __restrict__ S, const u16* __restrict__ Wtm2,
               const float* __restrict__ mb2, const int* __restrict__ deg,
               const u16* __restrict__ xb, const u16* __restrict__ xt,
               u16* __restrict__ U)
{
  __shared__ u16 sh[26112];   // attn: XaS 8704 + XbS 17408 ; gemm: 16384
  const int b = blockIdx.x, t = threadIdx.x;
  if (b < 256){
    gemm_body<true,u16>(S, 512, Wtm2, mb2, deg,
                        U, 512, 512, b >> 7, b & 127, sh, t);
    return;
  }
  const int a = b - 256;
  const int side = a >> 7;
  const int g = a & 63, h = (a >> 6) & 1;
  const u16* Xa = xb + (size_t)side * NN * DD;
  const u16* Xb = xb + (size_t)(1 - side) * NN * DD;
  const u16* Xt = xt + (size_t)(1 - side) * DD * NN;
  u16* Uside = U + (size_t)side * NN * 512;

  u16* XaS = sh;            // 64*136
  u16* XbS = sh + 8704;     // 128*136

  const int w = t >> 6, lane = t & 63;
  const int lr = lane & 15, lq = lane >> 4;

  {
    const u16* sa = Xa + ((size_t)g * GS + h * 64) * DD;
    #pragma unroll
    for (int i = 0; i < 4; i++){
      int s = i * 256 + t; int r = s >> 4, c8 = (s & 15) << 3;
      *(uint4*)&XaS[r * 136 + c8] = *(const uint4*)(sa + (size_t)r * DD + c8);
    }
    const u16* sb = Xb + (size_t)g * GS * DD;
    #pragma unroll
    for (int i = 0; i < 8; i++){
      int s = i * 256 + t; int r = s >> 4, c8 = (s & 15) << 3;
      *(uint4*)&XbS[r * 136 + c8] = *(const uint4*)(sb + (size_t)r * DD + c8);
    }
  }
  __syncthreads();

  f32x4 sc[8];
  #pragma unroll
  for (int ct = 0; ct < 8; ct++) sc[ct] = (f32x4){0.f, 0.f, 0.f, 0.f};
  #pragma unroll
  for (int kb = 0; kb < 4; kb++){
    bf16x8 aa = *(const bf16x8*)&XaS[(w * 16 + lr) * 136 + kb * 32 + (lq << 3)];
    #pragma unroll
    for (int ct = 0; ct < 8; ct++){
      bf16x8 bb = *(const bf16x8*)&XbS[(ct * 16 + lr) * 136 + kb * 32 + (lq << 3)];
      sc[ct] = __builtin_amdgcn_mfma_f32_16x16x32_bf16(aa, bb, sc[ct], 0, 0, 0);
    }
  }
  float inv[4];
  #pragma unroll
  for (int rr = 0; rr < 4; rr++){
    float m = sc[0][rr];
    #pragma unroll
    for (int ct = 1; ct < 8; ct++) m = fmaxf(m, sc[ct][rr]);
    #pragma unroll
    for (int sh_ = 1; sh_ < 16; sh_ <<= 1) m = fmaxf(m, __shfl_xor(m, sh_, 64));
    float s = 0.f;
    #pragma unroll
    for (int ct = 0; ct < 8; ct++){
      float e = __expf(sc[ct][rr] - m);
      sc[ct][rr] = e; s += e;
    }
    #pragma unroll
    for (int sh_ = 1; sh_ < 16; sh_ <<= 1) s += __shfl_xor(s, sh_, 64);
    inv[rr] = 1.f / s;
  }
  #pragma unroll
  for (int ct = 0; ct < 8; ct++)
    #pragma unroll
    for (int rr = 0; rr < 4; rr++)
      XaS[(w * 16 + lq * 4 + rr) * 136 + ct * 16 + lr] = f2bf(sc[ct][rr] * inv[rr]);
  __syncthreads();

  f32x4 o[8];
  #pragma unroll
  for (int ct = 0; ct < 8; ct++) o[ct] = (f32x4){0.f, 0.f, 0.f, 0.f};
  #pragma unroll
  for (int kb = 0; kb < 4; kb++){
    bf16x8 aa = *(const bf16x8*)&XaS[(w * 16 + lr) * 136 + kb * 32 + (lq << 3)];
    #pragma unroll
    for (int ct = 0; ct < 8; ct++){
      bf16x8 bb = *(const bf16x8*)(Xt + (size_t)(ct * 16 + lr) * NN + g * GS + kb * 32 + (lq << 3));
      o[ct] = __builtin_amdgcn_mfma_f32_16x16x32_bf16(aa, bb, o[ct], 0, 0, 0);
    }
  }
  const u16* XaG = Xa + ((size_t)g * GS + h * 64) * DD;
  #pragma unroll
  for (int ct = 0; ct < 8; ct++)
    #pragma unroll
    for (int rr = 0; rr < 4; rr++){
      int row = w * 16 + lq * 4 + rr, col = ct * 16 + lr;
      float xa = bf2f(XaG[(size_t)row * DD + col]);
      Uside[((size_t)g * GS + h * 64 + row) * 512 + 256 + col] = f2bf(xa - o[ct][rr]);
    }
}

// ---- upd_k: fused update net. 64 rows/block, 512 threads (2x4 wave grid).
// H1 [64][520], H2 [64][264] in LDS; B weights streamed counted-vmcnt;
// G1's A operand loads straight to registers from global (L2-hot, 4x reuse).
__global__ __launch_bounds__(512)
void upd_k(const u16* __restrict__ U,
           const u16* __restrict__ Wtu1, const float* __restrict__ ub1,
           const u16* __restrict__ Wtu2, const float* __restrict__ ub2,
           const u16* __restrict__ Wtu3, const float* __restrict__ ub3,
           const float* __restrict__ x1, const float* __restrict__ x2,
           float* __restrict__ out)
{
  __shared__ u16 sh[66560];   // 133120 B
  u16* H1s  = sh;             // 64*520 = 33280
  u16* H2s  = sh + 33280;     // 64*264 = 16896
  u16* Bst0 = sh + 50176;     // 8192 (1024 slots of 8)
  u16* Bst1 = sh + 58368;     // 8192

  const int t = threadIdx.x;
  const int w = t >> 6, lane = t & 63;
  const int wr = w >> 2, wc = w & 3;     // 2 (rows) x 4 (cols) waves
  const int lr = lane & 15, lq = lane >> 4;
  const int r0 = blockIdx.x << 6;

  const int sB0 = t, sB1 = t + 512;      // B slots
  const int cB0 = sB0 >> 2, cB1 = sB1 >> 2;
  const int swB0 = (((sB0 & 3) ^ (cB0 & 3)) << 3);
  const int swB1 = (((sB1 & 3) ^ (cB1 & 3)) << 3);
  const int swr = ((lq ^ (lr & 3)) << 3);

  f32x4 acc[2][4];
  auto zacc = [&](){
    #pragma unroll
    for (int i = 0; i < 2; i++)
      #pragma unroll
      for (int j = 0; j < 4; j++) acc[i][j] = (f32x4){0.f, 0.f, 0.f, 0.f};
  };

  // ---- G1: H1 = relu(U @ Wtu1^T + b1), K=512, 512 cols in 2 halves ----
  bf16x8 afA[2], afB[2];
  auto ldA = [&](int kb, bf16x8 (&af)[2]){
    #pragma unroll
    for (int mi = 0; mi < 2; mi++)
      af[mi] = *(const bf16x8*)&U[(size_t)(r0 + wr * 32 + mi * 16 + lr) * 512 + kb + (lq << 3)];
  };
  auto compA = [&](const bf16x8 (&af)[2], const u16* Bsb){
    bf16x8 bfv[4];
    #pragma unroll
    for (int ct = 0; ct < 4; ct++)
      bfv[ct] = *(const bf16x8*)&Bsb[(wc * 64 + ct * 16 + lr) * 32 + swr];
    #pragma unroll
    for (int mi = 0; mi < 2; mi++)
      #pragma unroll
      for (int ct = 0; ct < 4; ct++)
        acc[mi][ct] = __builtin_amdgcn_mfma_f32_16x16x32_bf16(af[mi], bfv[ct], acc[mi][ct], 0, 0, 0);
  };
  for (int hN = 0; hN < 2; hN++){
    zacc();
    auto stB = [&](int kb, u16* dst){
      gload16(Wtu1 + (size_t)(hN * 256 + cB0) * 512 + kb + swB0, dst + sB0 * 8);
      gload16(Wtu1 + (size_t)(hN * 256 + cB1) * 512 + kb + swB1, dst + sB1 * 8);
    };
    stB(0, Bst0);
    ldA(0, afA);
    for (int i2 = 0; i2 < 8; i2++){
      const int kb = i2 << 6;
      stB(kb + 32, Bst1); ldA(kb + 32, afB);
      wbar<4>();                     // waits stB(kb)+ldA(kb); newer 4 in flight
      compA(afA, Bst0);
      bar();
      if (i2 < 7){
        stB(kb + 64, Bst0); ldA(kb + 64, afA);
        wbar<4>();
      } else {
        wbar<0>();
      }
      compA(afB, Bst1);
      bar();
    }
    #pragma unroll
    for (int mi = 0; mi < 2; mi++)
      #pragma unroll
      for (int ct = 0; ct < 4; ct++)
        #pragma unroll
        for (int rr = 0; rr < 4; rr++){
          int row = wr * 32 + mi * 16 + lq * 4 + rr;
          int col = wc * 64 + ct * 16 + lr;
          float v = acc[mi][ct][rr] + ub1[hN * 256 + col];
          H1s[row * 520 + hN * 256 + col] = f2bf(fmaxf(v, 0.f));
        }
  }
  __syncthreads();

  // ---- G2: H2 = relu(H1 @ Wtu2^T + b2), K=512, 256 cols ----
  zacc();
  {
    auto stB = [&](int kb, u16* dst){
      gload16(Wtu2 + (size_t)cB0 * 512 + kb + swB0, dst + sB0 * 8);
      gload16(Wtu2 + (size_t)cB1 * 512 + kb + swB1, dst + sB1 * 8);
    };
    auto comp = [&](int kb, const u16* Bsb){
      bf16x8 af[2], bfv[4];
      #pragma unroll
      for (int mi = 0; mi < 2; mi++)
        af[mi] = *(const bf16x8*)&H1s[(wr * 32 + mi * 16 + lr) * 520 + kb + (lq << 3)];
      #pragma unroll
      for (int ct = 0; ct < 4; ct++)
        bfv[ct] = *(const bf16x8*)&Bsb[(wc * 64 + ct * 16 + lr) * 32 + swr];
      #pragma unroll
      for (int mi = 0; mi < 2; mi++)
        #pragma unroll
        for (int ct = 0; ct < 4; ct++)
          acc[mi][ct] = __builtin_amdgcn_mfma_f32_16x16x32_bf16(af[mi], bfv[ct], acc[mi][ct], 0, 0, 0);
    };
    stB(0, Bst0);
    for (int i2 = 0; i2 < 8; i2++){
      const int kb = i2 << 6;
      stB(kb + 32, Bst1);
      wbar<2>();
      comp(kb, Bst0);
      bar();
      if (i2 < 7){
        stB(kb + 64, Bst0);
        wbar<2>();
      } else {
        wbar<0>();
      }
      comp(kb + 32, Bst1);
      bar();
    }
    #pragma unroll
    for (int mi = 0; mi < 2; mi++)
      #pragma unroll
      for (int ct = 0; ct < 4; ct++)
        #pragma unroll
        for (int rr = 0; rr < 4; rr++){
          int row = wr * 32 + mi * 16 + lq * 4 + rr;
          int col = wc * 64 + ct * 16 + lr;
          H2s[row * 264 + col] = f2bf(fmaxf(acc[mi][ct][rr] + ub2[col], 0.f));
        }
  }
  __syncthreads();

  // ---- G3: out = x + H2 @ Wtu3^T + b3, K=256, 128 cols ----
  zacc();
  {
    auto stB = [&](int kb, u16* dst){
      gload16(Wtu3 + (size_t)cB0 * 256 + kb + swB0, dst + sB0 * 8);   // 512 slots
    };
    auto comp = [&](int kb, const u16* Bsb){
      bf16x8 af[2], bfv[2];
      #pragma unroll
      for (int mi = 0; mi < 2; mi++)
        af[mi] = *(const bf16x8*)&H2s[(wr * 32 + mi * 16 + lr) * 264 + kb + (lq << 3)];
      #pragma unroll
      for (int ct = 0; ct < 2; ct++)
        bfv[ct] = *(const bf16x8*)&Bsb[(wc * 32 + ct * 16 + lr) * 32 + swr];
      #pragma unroll
      for (int mi = 0; mi < 2; mi++)
        #pragma unroll
        for (int ct = 0; ct < 2; ct++)
          acc[mi][ct] = __builtin_amdgcn_mfma_f32_16x16x32_bf16(af[mi], bfv[ct], acc[mi][ct], 0, 0, 0);
    };
    stB(0, Bst0);
    for (int i2 = 0; i2 < 4; i2++){
      const int kb = i2 << 6;
      stB(kb + 32, Bst1);
      wbar<1>();
      comp(kb, Bst0);
      bar();
      if (i2 < 3){
        stB(kb + 64, Bst0);
        wbar<1>();
      } else {
        wbar<0>();
      }
      comp(kb + 32, Bst1);
      bar();
    }
    #pragma unroll
    for (int mi = 0; mi < 2; mi++)
      #pragma unroll
      for (int ct = 0; ct < 2; ct++)
        #pragma unroll
        for (int rr = 0; rr < 4; rr++){
          int row = wr * 32 + mi * 16 + lq * 4 + rr;
          int col = wc * 32 + ct * 16 + lr;
          int grow = r0 + row;
          const float* rp = (grow < NN) ? x1 : x2;
          float v = acc[mi][ct][rr] + ub3[col]
                  + rp[(size_t)(grow & (NN - 1)) * 128 + col];
          out[(size_t)grow * 128 + col] = v;
        }
  }
}

extern "C" void kernel_launch(void* const* d_in, const int* in_sizes, int n_in,
                              void* d_out, int out_size, void* d_ws, size_t ws_size,
                              hipStream_t stream)
{
  const float* x1  = (const float*)d_in[0];
  const int*   ei1 = (const int*)  d_in[1];
  const float* x2  = (const float*)d_in[3];
  const int*   ei2 = (const int*)  d_in[4];
  const float* mW1 = (const float*)d_in[6];
  const float* mb1 = (const float*)d_in[7];
  const float* mW2 = (const float*)d_in[8];
  const float* mb2 = (const float*)d_in[9];
  const float* uW1 = (const float*)d_in[10];
  const float* ub1 = (const float*)d_in[11];
  const float* uW2 = (const float*)d_in[12];
  const float* ub2 = (const float*)d_in[13];
  const float* uW3 = (const float*)d_in[14];
  const float* ub3 = (const float*)d_in[15];
  float* out = (float*)d_out;

  char* w = (char*)d_ws;
  auto alloc = [&](size_t b){ char* p = w; w += (b + 255) & ~(size_t)255; return p; };
  u16*  S    = (u16*)alloc((size_t)2 * NN * 512 * 2);
  u16*  PQ   = (u16*)alloc((size_t)2 * NN * 1024 * 2);
  u16*  xb   = (u16*)alloc((size_t)2 * NN * DD * 2);
  u16*  xt   = (u16*)alloc((size_t)2 * DD * NN * 2);
  u16*  U    = (u16*)alloc((size_t)2 * NN * 512 * 2);
  int*  deg  = (int*)alloc((size_t)2 * NN * 4);
  int*  offs1 = (int*)alloc((NN + 1) * 4);
  int*  offs2 = (int*)alloc((NN + 1) * 4);
  int*  cur1  = (int*)alloc(NN * 4);
  int*  cur2  = (int*)alloc(NN * 4);
  int*  srt1  = (int*)alloc((size_t)EE * 4);
  int*  srt2  = (int*)alloc((size_t)EE * 4);
  u16*  WtPQ = (u16*)alloc(1024 * 128 * 2);
  float* bPQ = (float*)alloc(1024 * 4);
  u16*  Wtm2 = (u16*)alloc(256 * 512 * 2);
  u16*  Wtu1 = (u16*)alloc(512 * 512 * 2);
  u16*  Wtu2 = (u16*)alloc(256 * 512 * 2);
  u16*  Wtu3 = (u16*)alloc(128 * 256 * 2);

  hipMemsetAsync(deg, 0, (size_t)2 * NN * 4, stream);

  pre_k<<<3497, 256, 0, stream>>>(
      mW1, mb1, mW2, uW1, uW2, uW3, x1, x2, ei1, ei2,
      WtPQ, bPQ, Wtm2, Wtu1, Wtu2, Wtu3, xb, xt, U, deg);

  scan_k<<<2, 256, 0, stream>>>(deg, offs1, cur1, offs2, cur2);

  mid_k<<<2048, 256, 0, stream>>>(xb, WtPQ, bPQ, PQ, ei1, ei2,
                                  cur1, cur2, srt1, srt2);

  gather_k<<<dim3(NN / 4, 2), 256, 0, stream>>>(offs1, srt1, offs2, srt2, PQ, S);

  msgattn_k<<<512, 256, 0, stream>>>(S, Wtm2, mb2, deg, xb, xt, U);

  upd_k<<<256, 512, 0, stream>>>(U, Wtu1, ub1, Wtu2, ub2, Wtu3, ub3,
                                 x1, x2, out);
}

// Round 10
// 218.165 us; speedup vs baseline: 1.4547x; 1.0094x over previous
//
#include <hip/hip_runtime.h>
#include <stdint.h>

// GMNConv R15 = R14 with the msg GEMM fused into upd_k as a G0 phase
// (block-LOCAL fusion: each block computes U[rows,0:256] for its own 64 rows,
// stores to global, vmcnt(0)-drains, then G1 reads them back L2-hot — no
// cross-block handoff, unlike the R12 scan fiasco). attn returns to mid_k
// (R13-proven placement; R13's regression was msg-ALONE, now moot).
// msgattn_k deleted -> 5 dispatches.
//  pre_k    : weight transpose (tiled) + bPQ + x cast (+U x-cols) + x transpose + histogram
//  scan_k   : exclusive prefix scan of deg -> offs/cur
//  mid_k    : PQ = xb@WtPQ^T + bPQ (single-shot MFMA) || scatter || attention
//  gather_k : S[n] = sum relu(P[src]+Q[n])  (16/8/4/1 unroll)
//  upd_k    : G0 msg = S@Wtm2^T + deg*mb2 -> U[:,0:256];
//             G1 H1 = relu(U@uW1+b1) [LDS]; G2 H2 = relu(H1@uW2+b2) [LDS];
//             G3 out = x + H2@uW3+b3

typedef unsigned short u16;
typedef __bf16 bf16x8 __attribute__((ext_vector_type(8)));
typedef float f32x4 __attribute__((ext_vector_type(4)));

#define NN 8192
#define DD 128
#define EE 131072
#define GS 128
#define NG 64

__device__ __forceinline__ float bf2f(u16 u){
  return __uint_as_float(((uint32_t)u) << 16);
}
__device__ __forceinline__ u16 f2bf(float f){
  uint32_t x = __float_as_uint(f);
  return (u16)((x + 0x7fffu + ((x >> 16) & 1u)) >> 16);
}
__device__ __forceinline__ void gload16(const u16* g, u16* l){
  __builtin_amdgcn_global_load_lds(
      (const __attribute__((address_space(1))) uint32_t*)(uintptr_t)g,
      (__attribute__((address_space(3))) uint32_t*)(uintptr_t)l, 16, 0, 0);
}
// counted-vmcnt fence + barrier (T4: N>0 keeps newer loads in flight)
template<int N>
__device__ __forceinline__ void wbar(){
  if constexpr (N == 0)      asm volatile("s_waitcnt vmcnt(0)" ::: "memory");
  else if constexpr (N == 1) asm volatile("s_waitcnt vmcnt(1)" ::: "memory");
  else if constexpr (N == 2) asm volatile("s_waitcnt vmcnt(2)" ::: "memory");
  else if constexpr (N == 4) asm volatile("s_waitcnt vmcnt(4)" ::: "memory");
  __builtin_amdgcn_s_barrier();
  __builtin_amdgcn_sched_barrier(0);
}
__device__ __forceinline__ void bar(){
  __builtin_amdgcn_s_barrier();
  __builtin_amdgcn_sched_barrier(0);
}

// ---- pq_gemm: C[128x128] = A[128x128] @ Wt[128x128]^T + bias ----
// Single-shot: both 32KB tiles staged once, ONE vmcnt(0) fence, then 64 MFMA
// with no further barriers. Row stride 128 u16 (256B); slot p of row r holds
// logical 16B-chunk p ^ (r&7) (2-way bank alias on read = free).
__device__ __forceinline__ void pq_gemm(
    const u16* __restrict__ A, const u16* __restrict__ Wt,
    const float* __restrict__ bias, u16* __restrict__ out,
    int bx, int by, u16* __restrict__ sh, int t)
{
  u16* As = sh;             // 16384 u16
  u16* Bs = sh + 16384;     // 16384 u16
  const int brow = by << 7, bcol = bx << 7;
  const int w = t >> 6, lane = t & 63;
  const int rb = (w >> 1) << 6, cb = (w & 1) << 6;
  const int lr = lane & 15, lq = lane >> 4;

  #pragma unroll
  for (int i = 0; i < 8; i++){
    int sg = i * 256 + t;
    int r = sg >> 4, p = sg & 15;
    int l = p ^ (r & 7);
    gload16(A  + (size_t)(brow + r) * 128 + (l << 3), As + sg * 8);
    gload16(Wt + (size_t)(bcol + r) * 128 + (l << 3), Bs + sg * 8);
  }
  wbar<0>();

  f32x4 acc[4][4];
  #pragma unroll
  for (int i = 0; i < 4; i++)
    #pragma unroll
    for (int j = 0; j < 4; j++) acc[i][j] = (f32x4){0.f, 0.f, 0.f, 0.f};

  #pragma unroll
  for (int kb = 0; kb < 4; kb++){
    bf16x8 af[4], bfr[4];
    #pragma unroll
    for (int mi = 0; mi < 4; mi++){
      int row = rb + mi * 16 + lr;
      af[mi] = *(const bf16x8*)&As[(row << 7) + ((((kb << 2) | lq) ^ (row & 7)) << 3)];
    }
    #pragma unroll
    for (int ni = 0; ni < 4; ni++){
      int row = cb + ni * 16 + lr;
      bfr[ni] = *(const bf16x8*)&Bs[(row << 7) + ((((kb << 2) | lq) ^ (row & 7)) << 3)];
    }
    #pragma unroll
    for (int mi = 0; mi < 4; mi++)
      #pragma unroll
      for (int ni = 0; ni < 4; ni++)
        acc[mi][ni] = __builtin_amdgcn_mfma_f32_16x16x32_bf16(af[mi], bfr[ni], acc[mi][ni], 0, 0, 0);
  }

  #pragma unroll
  for (int mi = 0; mi < 4; mi++)
    #pragma unroll
    for (int ni = 0; ni < 4; ni++)
      #pragma unroll
      for (int rr = 0; rr < 4; rr++){
        int grow = brow + rb + mi * 16 + lq * 4 + rr;
        int gcol = bcol + cb + ni * 16 + lr;
        out[(size_t)grow * 1024 + gcol] = f2bf(acc[mi][ni][rr] + bias[gcol]);
      }
}

// ---- pre_k: tiled weight transpose | bPQ | cast x | transpose x | histogram ----
// Block layout: [0,168) weight 64x64 tiles; 168 bPQ; [169,2217) x cast;
// [2217,2473) x transpose; [2473,3497) histogram.
__global__ __launch_bounds__(256)
void pre_k(const float* __restrict__ mW1, const float* __restrict__ mb1,
           const float* __restrict__ mW2, const float* __restrict__ uW1,
           const float* __restrict__ uW2, const float* __restrict__ uW3,
           const float* __restrict__ x1, const float* __restrict__ x2,
           const int* __restrict__ ei1, const int* __restrict__ ei2,
           u16* __restrict__ WtPQ, float* __restrict__ bPQ,
           u16* __restrict__ Wtm2, u16* __restrict__ Wtu1,
           u16* __restrict__ Wtu2, u16* __restrict__ Wtu3,
           u16* __restrict__ xb, u16* __restrict__ xt,
           u16* __restrict__ U, int* __restrict__ deg)
{
  __shared__ u16 T[8704];     // weight tiles use 64*68=4352; x-transpose 64*136
  int b = blockIdx.x, t = threadIdx.x;
  if (b < 168){
    // one 64x64 tile of dst[c][k] = f2bf(src[k][c])
    const float* srcs[6] = {mW1, mW1 + 128 * 512, mW2, uW1, uW2, uW3};
    u16* dsts[6] = {WtPQ, WtPQ + 512 * 128, Wtm2, Wtu1, Wtu2, Wtu3};
    const int ldSs[6] = {512, 512, 256, 512, 256, 128};
    const int ldDs[6] = {128, 128, 512, 512, 512, 256};
    const int jb[7]   = {0, 16, 32, 64, 128, 160, 168};
    int j = 0;
    while (b >= jb[j + 1]) j++;
    const int l = b - jb[j];
    const int ldS = ldSs[j], ldD = ldDs[j];
    const int ntc = ldS >> 6;              // C/64
    const int k0 = (l / ntc) << 6, c0 = (l % ntc) << 6;
    const float* S = srcs[j];
    u16* D = dsts[j];
    #pragma unroll
    for (int i = 0; i < 4; i++){
      int s = i * 256 + t;
      int r = s >> 4, c4 = (s & 15) << 2;
      float4 v = *(const float4*)&S[(size_t)(k0 + r) * ldS + c0 + c4];
      uint2 pk;
      pk.x = (uint32_t)f2bf(v.x) | ((uint32_t)f2bf(v.y) << 16);
      pk.y = (uint32_t)f2bf(v.z) | ((uint32_t)f2bf(v.w) << 16);
      *(uint2*)&T[r * 68 + c4] = pk;
    }
    __syncthreads();
    #pragma unroll
    for (int i = 0; i < 4; i++){
      int s = i * 256 + t;
      int c = s >> 4, k4 = (s & 15) << 2;
      uint32_t a0 = T[(k4 + 0) * 68 + c];
      uint32_t a1 = T[(k4 + 1) * 68 + c];
      uint32_t a2 = T[(k4 + 2) * 68 + c];
      uint32_t a3 = T[(k4 + 3) * 68 + c];
      uint2 pk; pk.x = a0 | (a1 << 16); pk.y = a2 | (a3 << 16);
      *(uint2*)&D[(size_t)(c0 + c) * ldD + k0 + k4] = pk;
    }
  } else if (b == 168){
    #pragma unroll
    for (int i = 0; i < 4; i++){
      int idx = i * 256 + t;
      bPQ[idx] = (idx < 512) ? 0.f : mb1[idx - 512];
    }
  } else if (b < 2217){
    // cast x -> xb + U x-columns (float4 vectorized)
    int a = b - 169;
    int side = a >> 10, blk = a & 1023;
    const float* x = side ? x2 : x1;
    int i4 = blk * 256 + t;                 // float4 index within side
    float4 v = *(const float4*)&x[(size_t)i4 * 4];
    uint2 pk;
    pk.x = (uint32_t)f2bf(v.x) | ((uint32_t)f2bf(v.y) << 16);
    pk.y = (uint32_t)f2bf(v.z) | ((uint32_t)f2bf(v.w) << 16);
    *(uint2*)&xb[(size_t)side * NN * DD + (size_t)i4 * 4] = pk;
    int n = i4 >> 5, d = (i4 << 2) & 127;
    *(uint2*)&U[((size_t)side * NN + n) * 512 + 384 + d] = pk;
  } else if (b < 2473){
    // transpose: xt[side][d][n] = bf16(x[side][n][d]), 64-node tile
    int a = b - 2217;
    int side = a >> 7, blk = a & 127;
    const float* x = side ? x2 : x1;
    u16* dst = xt + (size_t)side * DD * NN;
    const int n0 = blk * 64;
    #pragma unroll
    for (int i = 0; i < 8; i++){
      int s = i * 256 + t;
      int r = s >> 5, c4 = (s & 31) << 2;
      float4 v = *(const float4*)&x[(size_t)(n0 + r) * DD + c4];
      uint2 pk;
      pk.x = (uint32_t)f2bf(v.x) | ((uint32_t)f2bf(v.y) << 16);
      pk.y = (uint32_t)f2bf(v.z) | ((uint32_t)f2bf(v.w) << 16);
      *(uint2*)&T[r * 136 + c4] = pk;
    }
    __syncthreads();
    #pragma unroll
    for (int i = 0; i < 8; i++){
      int s = i * 256 + t;
      int d = s >> 4, n4 = (s & 15) << 2;
      uint32_t a0 = T[(n4 + 0) * 136 + d];
      uint32_t a1 = T[(n4 + 1) * 136 + d];
      uint32_t a2 = T[(n4 + 2) * 136 + d];
      uint32_t a3 = T[(n4 + 3) * 136 + d];
      uint2 pk; pk.x = a0 | (a1 << 16); pk.y = a2 | (a3 << 16);
      *(uint2*)(dst + (size_t)d * NN + n0 + n4) = pk;
    }
  } else {
    // histogram
    int a = b - 2473;
    int side = a >> 9, blk = a & 511;
    const int* ei = side ? ei2 : ei1;
    int e = blk * 256 + t;
    atomicAdd(&deg[side * NN + ei[e]], 1);
  }
}

// ---- exclusive prefix scan over NN=8192 ints; one block per side ----
__global__ __launch_bounds__(256)
void scan_k(const int* __restrict__ deg,
            int* __restrict__ offs1, int* __restrict__ cur1,
            int* __restrict__ offs2, int* __restrict__ cur2){
  const int* d = deg + blockIdx.x * NN;
  int* offs = blockIdx.x ? offs2 : offs1;
  int* cur  = blockIdx.x ? cur2  : cur1;
  __shared__ int part[256];
  const int t = threadIdx.x;
  const int base = t * 32;
  int loc[32];
  int s = 0;
  #pragma unroll
  for (int i = 0; i < 32; i++){ loc[i] = s; s += d[base + i]; }
  part[t] = s;
  __syncthreads();
  for (int off = 1; off < 256; off <<= 1){
    int v = (t >= off) ? part[t - off] : 0;
    __syncthreads();
    part[t] += v;
    __syncthreads();
  }
  int pre = (t == 0) ? 0 : part[t - 1];
  #pragma unroll
  for (int i = 0; i < 32; i++){
    int o = pre + loc[i];
    offs[base + i] = o;
    cur[base + i]  = o;
  }
  if (t == 255) offs[NN] = part[255];
}

// ---- mid_k: PQ GEMM (single-shot) | scatter edges | cross-attention ----
__global__ __launch_bounds__(256)
void mid_k(const u16* __restrict__ xb, const u16* __restrict__ WtPQ,
           const float* __restrict__ bPQ, u16* __restrict__ PQ,
           const int* __restrict__ ei1, const int* __restrict__ ei2,
           int* __restrict__ cur1, int* __restrict__ cur2,
           int* __restrict__ srt1, int* __restrict__ srt2,
           const u16* __restrict__ xt, u16* __restrict__ U)
{
  __shared__ u16 sh[32768];   // pq: 64KB; attn: XaS 8704 + XbS 17408 = 52KB
  const int b = blockIdx.x, t = threadIdx.x;
  if (b < 1024){
    pq_gemm(xb, WtPQ, bPQ, PQ, b >> 7, b & 127, sh, t);
    return;
  }
  if (b < 2048){
    int a = b - 1024;
    int side = a >> 9, blk = a & 511;
    const int* ei = side ? ei2 : ei1;
    int* cur = side ? cur2 : cur1;
    int* srt = side ? srt2 : srt1;
    int e = blk * 256 + t;
    int tgt = ei[e], src = ei[EE + e];
    int p = atomicAdd(&cur[tgt], 1);
    srt[p] = src;
    return;
  }
  // ---- block-diagonal cross-attention (depends only on pre_k) ----
  const int a = b - 2048;
  const int side = a >> 7;
  const int g = a & 63, h = (a >> 6) & 1;
  const u16* Xa = xb + (size_t)side * NN * DD;
  const u16* Xb = xb + (size_t)(1 - side) * NN * DD;
  const u16* Xt = xt + (size_t)(1 - side) * DD * NN;
  u16* Uside = U + (size_t)side * NN * 512;

  u16* XaS = sh;            // 64*136
  u16* XbS = sh + 8704;     // 128*136

  const int w = t >> 6, lane = t & 63;
  const int lr = lane & 15, lq = lane >> 4;

  {
    const u16* sa = Xa + ((size_t)g * GS + h * 64) * DD;
    #pragma unroll
    for (int i = 0; i < 4; i++){
      int s = i * 256 + t; int r = s >> 4, c8 = (s & 15) << 3;
      *(uint4*)&XaS[r * 136 + c8] = *(const uint4*)(sa + (size_t)r * DD + c8);
    }
    const u16* sb = Xb + (size_t)g * GS * DD;
    #pragma unroll
    for (int i = 0; i < 8; i++){
      int s = i * 256 + t; int r = s >> 4, c8 = (s & 15) << 3;
      *(uint4*)&XbS[r * 136 + c8] = *(const uint4*)(sb + (size_t)r * DD + c8);
    }
  }
  __syncthreads();

  f32x4 sc[8];
  #pragma unroll
  for (int ct = 0; ct < 8; ct++) sc[ct] = (f32x4){0.f, 0.f, 0.f, 0.f};
  #pragma unroll
  for (int kb = 0; kb < 4; kb++){
    bf16x8 aa = *(const bf16x8*)&XaS[(w * 16 + lr) * 136 + kb * 32 + (lq << 3)];
    #pragma unroll
    for (int ct = 0; ct < 8; ct++){
      bf16x8 bb = *(const bf16x8*)&XbS[(ct * 16 + lr) * 136 + kb * 32 + (lq << 3)];
      sc[ct] = __builtin_amdgcn_mfma_f32_16x16x32_bf16(aa, bb, sc[ct], 0, 0, 0);
    }
  }
  float inv[4];
  #pragma unroll
  for (int rr = 0; rr < 4; rr++){
    float m = sc[0][rr];
    #pragma unroll
    for (int ct = 1; ct < 8; ct++) m = fmaxf(m, sc[ct][rr]);
    #pragma unroll
    for (int sh_ = 1; sh_ < 16; sh_ <<= 1) m = fmaxf(m, __shfl_xor(m, sh_, 64));
    float s = 0.f;
    #pragma unroll
    for (int ct = 0; ct < 8; ct++){
      float e = __expf(sc[ct][rr] - m);
      sc[ct][rr] = e; s += e;
    }
    #pragma unroll
    for (int sh_ = 1; sh_ < 16; sh_ <<= 1) s += __shfl_xor(s, sh_, 64);
    inv[rr] = 1.f / s;
  }
  #pragma unroll
  for (int ct = 0; ct < 8; ct++)
    #pragma unroll
    for (int rr = 0; rr < 4; rr++)
      XaS[(w * 16 + lq * 4 + rr) * 136 + ct * 16 + lr] = f2bf(sc[ct][rr] * inv[rr]);
  __syncthreads();

  f32x4 o[8];
  #pragma unroll
  for (int ct = 0; ct < 8; ct++) o[ct] = (f32x4){0.f, 0.f, 0.f, 0.f};
  #pragma unroll
  for (int kb = 0; kb < 4; kb++){
    bf16x8 aa = *(const bf16x8*)&XaS[(w * 16 + lr) * 136 + kb * 32 + (lq << 3)];
    #pragma unroll
    for (int ct = 0; ct < 8; ct++){
      bf16x8 bb = *(const bf16x8*)(Xt + (size_t)(ct * 16 + lr) * NN + g * GS + kb * 32 + (lq << 3));
      o[ct] = __builtin_amdgcn_mfma_f32_16x16x32_bf16(aa, bb, o[ct], 0, 0, 0);
    }
  }
  const u16* XaG = Xa + ((size_t)g * GS + h * 64) * DD;
  #pragma unroll
  for (int ct = 0; ct < 8; ct++)
    #pragma unroll
    for (int rr = 0; rr < 4; rr++){
      int row = w * 16 + lq * 4 + rr, col = ct * 16 + lr;
      float xa = bf2f(XaG[(size_t)row * DD + col]);
      Uside[((size_t)g * GS + h * 64 + row) * 512 + 256 + col] = f2bf(xa - o[ct][rr]);
    }
}

// ---- gather: S[n] = sum relu(P[src]+Q[n]); 1 wave = 1 node; 16/8/4/1 ----
__global__ __launch_bounds__(256)
void gather_k(const int* __restrict__ offs1, const int* __restrict__ srt1,
              const int* __restrict__ offs2, const int* __restrict__ srt2,
              const u16* __restrict__ PQ, u16* __restrict__ S)
{
  const int side = blockIdx.y;
  const int* offs = side ? offs2 : offs1;
  const int* srt  = side ? srt2  : srt1;
  const u16* base = PQ + (size_t)side * NN * 1024;
  u16* Sb = S + (size_t)side * NN * 512;

  const int node = (blockIdx.x << 2) + (threadIdx.x >> 6);
  const int lane = threadIdx.x & 63;
  const int beg = offs[node], end = offs[node + 1];
  const u16* lbase = base + (lane << 3);

  uint4 qv = *(const uint4*)(base + (size_t)node * 1024 + 512 + (lane << 3));
  float q[8];
  {
    uint32_t qw[4] = {qv.x, qv.y, qv.z, qv.w};
    #pragma unroll
    for (int i = 0; i < 4; i++){
      q[i * 2]     = bf2f((u16)(qw[i] & 0xffffu));
      q[i * 2 + 1] = bf2f((u16)(qw[i] >> 16));
    }
  }
  float acc[8] = {0.f,0.f,0.f,0.f,0.f,0.f,0.f,0.f};

  int e = beg;
  for (; e + 15 < end; e += 16){
    int sx[16];
    #pragma unroll
    for (int i = 0; i < 16; i++) sx[i] = srt[e + i];
    uint4 pv[16];
    #pragma unroll
    for (int i = 0; i < 16; i++)
      pv[i] = *(const uint4*)(lbase + (size_t)sx[i] * 1024);
    #pragma unroll
    for (int i = 0; i < 16; i++){
      uint32_t w0[4] = {pv[i].x, pv[i].y, pv[i].z, pv[i].w};
      #pragma unroll
      for (int j = 0; j < 4; j++){
        acc[j*2]   += fmaxf(bf2f((u16)(w0[j] & 0xffffu)) + q[j*2],   0.f);
        acc[j*2+1] += fmaxf(bf2f((u16)(w0[j] >> 16))     + q[j*2+1], 0.f);
      }
    }
  }
  for (; e + 7 < end; e += 8){
    int sx[8];
    #pragma unroll
    for (int i = 0; i < 8; i++) sx[i] = srt[e + i];
    uint4 pv[8];
    #pragma unroll
    for (int i = 0; i < 8; i++)
      pv[i] = *(const uint4*)(lbase + (size_t)sx[i] * 1024);
    #pragma unroll
    for (int i = 0; i < 8; i++){
      uint32_t w0[4] = {pv[i].x, pv[i].y, pv[i].z, pv[i].w};
      #pragma unroll
      for (int j = 0; j < 4; j++){
        acc[j*2]   += fmaxf(bf2f((u16)(w0[j] & 0xffffu)) + q[j*2],   0.f);
        acc[j*2+1] += fmaxf(bf2f((u16)(w0[j] >> 16))     + q[j*2+1], 0.f);
      }
    }
  }
  for (; e + 3 < end; e += 4){
    int sx[4];
    #pragma unroll
    for (int i = 0; i < 4; i++) sx[i] = srt[e + i];
    uint4 pv[4];
    #pragma unroll
    for (int i = 0; i < 4; i++)
      pv[i] = *(const uint4*)(lbase + (size_t)sx[i] * 1024);
    #pragma unroll
    for (int i = 0; i < 4; i++){
      uint32_t w0[4] = {pv[i].x, pv[i].y, pv[i].z, pv[i].w};
      #pragma unroll
      for (int j = 0; j < 4; j++){
        acc[j*2]   += fmaxf(bf2f((u16)(w0[j] & 0xffffu)) + q[j*2],   0.f);
        acc[j*2+1] += fmaxf(bf2f((u16)(w0[j] >> 16))     + q[j*2+1], 0.f);
      }
    }
  }
  for (; e < end; e++){
    int sA = srt[e];
    uint4 pA = *(const uint4*)(lbase + (size_t)sA * 1024);
    uint32_t aw[4] = {pA.x, pA.y, pA.z, pA.w};
    #pragma unroll
    for (int i = 0; i < 4; i++){
      acc[i*2]   += fmaxf(bf2f((u16)(aw[i] & 0xffffu)) + q[i*2],   0.f);
      acc[i*2+1] += fmaxf(bf2f((u16)(aw[i] >> 16))     + q[i*2+1], 0.f);
    }
  }
  uint4 pk;
  pk.x = (uint32_t)f2bf(acc[0]) | ((uint32_t)f2bf(acc[1]) << 16);
  pk.y = (uint32_t)f2bf(acc[2]) | ((uint32_t)f2bf(acc[3]) << 16);
  pk.z = (uint32_t)f2bf(acc[4]) | ((uint32_t)f2bf(acc[5]) << 16);
  pk.w = (uint32_t)f2bf(acc[6]) | ((uint32_t)f2bf(acc[7]) << 16);
  *(uint4*)(Sb + (size_t)node * 512 + (lane << 3)) = pk;
}

// ---- upd_k: G0 msg + fused update net. 64 rows/block, 512 threads.
// G0 writes U[:,0:256] for this block's rows, vmcnt-drains, then G1 reads
// them back (same-block, L2-hot). H1 [64][520], H2 [64][264] in LDS.
__global__ __launch_bounds__(512)
void upd_k(const u16* __restrict__ Sg,
           const u16* __restrict__ Wtm2, const float* __restrict__ mb2,
           const int* __restrict__ deg, u16* __restrict__ U,
           const u16* __restrict__ Wtu1, const float* __restrict__ ub1,
           const u16* __restrict__ Wtu2, const float* __restrict__ ub2,
           const u16* __restrict__ Wtu3, const float* __restrict__ ub3,
           const float* __restrict__ x1, const float* __restrict__ x2,
           float* __restrict__ out)
{
  __shared__ u16 sh[66560];   // 133120 B
  u16* H1s  = sh;             // 64*520 = 33280
  u16* H2s  = sh + 33280;     // 64*264 = 16896
  u16* Bst0 = sh + 50176;     // 8192 (1024 slots of 8)
  u16* Bst1 = sh + 58368;     // 8192

  const int t = threadIdx.x;
  const int w = t >> 6, lane = t & 63;
  const int wr = w >> 2, wc = w & 3;     // 2 (rows) x 4 (cols) waves
  const int lr = lane & 15, lq = lane >> 4;
  const int r0 = blockIdx.x << 6;

  const int sB0 = t, sB1 = t + 512;      // B slots
  const int cB0 = sB0 >> 2, cB1 = sB1 >> 2;
  const int swB0 = (((sB0 & 3) ^ (cB0 & 3)) << 3);
  const int swB1 = (((sB1 & 3) ^ (cB1 & 3)) << 3);
  const int swr = ((lq ^ (lr & 3)) << 3);

  f32x4 acc[2][4];
  auto zacc = [&](){
    #pragma unroll
    for (int i = 0; i < 2; i++)
      #pragma unroll
      for (int j = 0; j < 4; j++) acc[i][j] = (f32x4){0.f, 0.f, 0.f, 0.f};
  };
  bf16x8 afA[2], afB[2];
  auto compA = [&](const bf16x8 (&af)[2], const u16* Bsb){
    bf16x8 bfv[4];
    #pragma unroll
    for (int ct = 0; ct < 4; ct++)
      bfv[ct] = *(const bf16x8*)&Bsb[(wc * 64 + ct * 16 + lr) * 32 + swr];
    #pragma unroll
    for (int mi = 0; mi < 2; mi++)
      #pragma unroll
      for (int ct = 0; ct < 4; ct++)
        acc[mi][ct] = __builtin_amdgcn_mfma_f32_16x16x32_bf16(af[mi], bfv[ct], acc[mi][ct], 0, 0, 0);
  };

  // ---- G0: U[:,0:256] = Sg @ Wtm2^T + deg*mb2 (this block's 64 rows) ----
  zacc();
  {
    auto ldS = [&](int kb, bf16x8 (&af)[2]){
      #pragma unroll
      for (int mi = 0; mi < 2; mi++)
        af[mi] = *(const bf16x8*)&Sg[(size_t)(r0 + wr * 32 + mi * 16 + lr) * 512 + kb + (lq << 3)];
    };
    auto stB = [&](int kb, u16* dst){
      gload16(Wtm2 + (size_t)cB0 * 512 + kb + swB0, dst + sB0 * 8);
      gload16(Wtm2 + (size_t)cB1 * 512 + kb + swB1, dst + sB1 * 8);
    };
    stB(0, Bst0);
    ldS(0, afA);
    for (int i2 = 0; i2 < 8; i2++){
      const int kb = i2 << 6;
      stB(kb + 32, Bst1); ldS(kb + 32, afB);
      wbar<4>();
      compA(afA, Bst0);
      bar();
      if (i2 < 7){
        stB(kb + 64, Bst0); ldS(kb + 64, afA);
        wbar<4>();
      } else {
        wbar<0>();
      }
      compA(afB, Bst1);
      bar();
    }
    #pragma unroll
    for (int mi = 0; mi < 2; mi++)
      #pragma unroll
      for (int ct = 0; ct < 4; ct++)
        #pragma unroll
        for (int rr = 0; rr < 4; rr++){
          int row = wr * 32 + mi * 16 + lq * 4 + rr;
          int col = wc * 64 + ct * 16 + lr;
          int grow = r0 + row;
          float v = acc[mi][ct][rr] + (float)deg[grow] * mb2[col];
          U[(size_t)grow * 512 + col] = f2bf(v);
        }
  }
  wbar<0>();   // drain G0 stores before G1 reads them back (block-local)

  // ---- G1: H1 = relu(U @ Wtu1^T + b1), K=512, 512 cols in 2 halves ----
  auto ldA = [&](int kb, bf16x8 (&af)[2]){
    #pragma unroll
    for (int mi = 0; mi < 2; mi++)
      af[mi] = *(const bf16x8*)&U[(size_t)(r0 + wr * 32 + mi * 16 + lr) * 512 + kb + (lq << 3)];
  };
  for (int hN = 0; hN < 2; hN++){
    zacc();
    auto stB = [&](int kb, u16* dst){
      gload16(Wtu1 + (size_t)(hN * 256 + cB0) * 512 + kb + swB0, dst + sB0 * 8);
      gload16(Wtu1 + (size_t)(hN * 256 + cB1) * 512 + kb + swB1, dst + sB1 * 8);
    };
    stB(0, Bst0);
    ldA(0, afA);
    for (int i2 = 0; i2 < 8; i2++){
      const int kb = i2 << 6;
      stB(kb + 32, Bst1); ldA(kb + 32, afB);
      wbar<4>();                     // waits stB(kb)+ldA(kb); newer 4 in flight
      compA(afA, Bst0);
      bar();
      if (i2 < 7){
        stB(kb + 64, Bst0); ldA(kb + 64, afA);
        wbar<4>();
      } else {
        wbar<0>();
      }
      compA(afB, Bst1);
      bar();
    }
    #pragma unroll
    for (int mi = 0; mi < 2; mi++)
      #pragma unroll
      for (int ct = 0; ct < 4; ct++)
        #pragma unroll
        for (int rr = 0; rr < 4; rr++){
          int row = wr * 32 + mi * 16 + lq * 4 + rr;
          int col = wc * 64 + ct * 16 + lr;
          float v = acc[mi][ct][rr] + ub1[hN * 256 + col];
          H1s[row * 520 + hN * 256 + col] = f2bf(fmaxf(v, 0.f));
        }
  }
  __syncthreads();

  // ---- G2: H2 = relu(H1 @ Wtu2^T + b2), K=512, 256 cols ----
  zacc();
  {
    auto stB = [&](int kb, u16* dst){
      gload16(Wtu2 + (size_t)cB0 * 512 + kb + swB0, dst + sB0 * 8);
      gload16(Wtu2 + (size_t)cB1 * 512 + kb + swB1, dst + sB1 * 8);
    };
    auto comp = [&](int kb, const u16* Bsb){
      bf16x8 af[2], bfv[4];
      #pragma unroll
      for (int mi = 0; mi < 2; mi++)
        af[mi] = *(const bf16x8*)&H1s[(wr * 32 + mi * 16 + lr) * 520 + kb + (lq << 3)];
      #pragma unroll
      for (int ct = 0; ct < 4; ct++)
        bfv[ct] = *(const bf16x8*)&Bsb[(wc * 64 + ct * 16 + lr) * 32 + swr];
      #pragma unroll
      for (int mi = 0; mi < 2; mi++)
        #pragma unroll
        for (int ct = 0; ct < 4; ct++)
          acc[mi][ct] = __builtin_amdgcn_mfma_f32_16x16x32_bf16(af[mi], bfv[ct], acc[mi][ct], 0, 0, 0);
    };
    stB(0, Bst0);
    for (int i2 = 0; i2 < 8; i2++){
      const int kb = i2 << 6;
      stB(kb + 32, Bst1);
      wbar<2>();
      comp(kb, Bst0);
      bar();
      if (i2 < 7){
        stB(kb + 64, Bst0);
        wbar<2>();
      } else {
        wbar<0>();
      }
      comp(kb + 32, Bst1);
      bar();
    }
    #pragma unroll
    for (int mi = 0; mi < 2; mi++)
      #pragma unroll
      for (int ct = 0; ct < 4; ct++)
        #pragma unroll
        for (int rr = 0; rr < 4; rr++){
          int row = wr * 32 + mi * 16 + lq * 4 + rr;
          int col = wc * 64 + ct * 16 + lr;
          H2s[row * 264 + col] = f2bf(fmaxf(acc[mi][ct][rr] + ub2[col], 0.f));
        }
  }
  __syncthreads();

  // ---- G3: out = x + H2 @ Wtu3^T + b3, K=256, 128 cols ----
  zacc();
  {
    auto stB = [&](int kb, u16* dst){
      gload16(Wtu3 + (size_t)cB0 * 256 + kb + swB0, dst + sB0 * 8);   // 512 slots
    };
    auto comp = [&](int kb, const u16* Bsb){
      bf16x8 af[2], bfv[2];
      #pragma unroll
      for (int mi = 0; mi < 2; mi++)
        af[mi] = *(const bf16x8*)&H2s[(wr * 32 + mi * 16 + lr) * 264 + kb + (lq << 3)];
      #pragma unroll
      for (int ct = 0; ct < 2; ct++)
        bfv[ct] = *(const bf16x8*)&Bsb[(wc * 32 + ct * 16 + lr) * 32 + swr];
      #pragma unroll
      for (int mi = 0; mi < 2; mi++)
        #pragma unroll
        for (int ct = 0; ct < 2; ct++)
          acc[mi][ct] = __builtin_amdgcn_mfma_f32_16x16x32_bf16(af[mi], bfv[ct], acc[mi][ct], 0, 0, 0);
    };
    stB(0, Bst0);
    for (int i2 = 0; i2 < 4; i2++){
      const int kb = i2 << 6;
      stB(kb + 32, Bst1);
      wbar<1>();
      comp(kb, Bst0);
      bar();
      if (i2 < 3){
        stB(kb + 64, Bst0);
        wbar<1>();
      } else {
        wbar<0>();
      }
      comp(kb + 32, Bst1);
      bar();
    }
    #pragma unroll
    for (int mi = 0; mi < 2; mi++)
      #pragma unroll
      for (int ct = 0; ct < 2; ct++)
        #pragma unroll
        for (int rr = 0; rr < 4; rr++){
          int row = wr * 32 + mi * 16 + lq * 4 + rr;
          int col = wc * 32 + ct * 16 + lr;
          int grow = r0 + row;
          const float* rp = (grow < NN) ? x1 : x2;
          float v = acc[mi][ct][rr] + ub3[col]
                  + rp[(size_t)(grow & (NN - 1)) * 128 + col];
          out[(size_t)grow * 128 + col] = v;
        }
  }
}

extern "C" void kernel_launch(void* const* d_in, const int* in_sizes, int n_in,
                              void* d_out, int out_size, void* d_ws, size_t ws_size,
                              hipStream_t stream)
{
  const float* x1  = (const float*)d_in[0];
  const int*   ei1 = (const int*)  d_in[1];
  const float* x2  = (const float*)d_in[3];
  const int*   ei2 = (const int*)  d_in[4];
  const float* mW1 = (const float*)d_in[6];
  const float* mb1 = (const float*)d_in[7];
  const float* mW2 = (const float*)d_in[8];
  const float* mb2 = (const float*)d_in[9];
  const float* uW1 = (const float*)d_in[10];
  const float* ub1 = (const float*)d_in[11];
  const float* uW2 = (const float*)d_in[12];
  const float* ub2 = (const float*)d_in[13];
  const float* uW3 = (const float*)d_in[14];
  const float* ub3 = (const float*)d_in[15];
  float* out = (float*)d_out;

  char* w = (char*)d_ws;
  auto alloc = [&](size_t b){ char* p = w; w += (b + 255) & ~(size_t)255; return p; };
  u16*  S    = (u16*)alloc((size_t)2 * NN * 512 * 2);
  u16*  PQ   = (u16*)alloc((size_t)2 * NN * 1024 * 2);
  u16*  xb   = (u16*)alloc((size_t)2 * NN * DD * 2);
  u16*  xt   = (u16*)alloc((size_t)2 * DD * NN * 2);
  u16*  U    = (u16*)alloc((size_t)2 * NN * 512 * 2);
  int*  deg  = (int*)alloc((size_t)2 * NN * 4);
  int*  offs1 = (int*)alloc((NN + 1) * 4);
  int*  offs2 = (int*)alloc((NN + 1) * 4);
  int*  cur1  = (int*)alloc(NN * 4);
  int*  cur2  = (int*)alloc(NN * 4);
  int*  srt1  = (int*)alloc((size_t)EE * 4);
  int*  srt2  = (int*)alloc((size_t)EE * 4);
  u16*  WtPQ = (u16*)alloc(1024 * 128 * 2);
  float* bPQ = (float*)alloc(1024 * 4);
  u16*  Wtm2 = (u16*)alloc(256 * 512 * 2);
  u16*  Wtu1 = (u16*)alloc(512 * 512 * 2);
  u16*  Wtu2 = (u16*)alloc(256 * 512 * 2);
  u16*  Wtu3 = (u16*)alloc(128 * 256 * 2);

  hipMemsetAsync(deg, 0, (size_t)2 * NN * 4, stream);

  pre_k<<<3497, 256, 0, stream>>>(
      mW1, mb1, mW2, uW1, uW2, uW3, x1, x2, ei1, ei2,
      WtPQ, bPQ, Wtm2, Wtu1, Wtu2, Wtu3, xb, xt, U, deg);

  scan_k<<<2, 256, 0, stream>>>(deg, offs1, cur1, offs2, cur2);

  mid_k<<<2304, 256, 0, stream>>>(xb, WtPQ, bPQ, PQ, ei1, ei2,
                                  cur1, cur2, srt1, srt2, xt, U);

  gather_k<<<dim3(NN / 4, 2), 256, 0, stream>>>(offs1, srt1, offs2, srt2, PQ, S);

  upd_k<<<256, 512, 0, stream>>>(S, Wtm2, mb2, deg, U,
                                 Wtu1, ub1, Wtu2, ub2, Wtu3, ub3,
                                 x1, x2, out);
}